// Round 10
// baseline (77.332 us; speedup 1.0000x reference)
//
#include <hip/hip_runtime.h>
#include <math.h>

#define HID 512
#define NSEQ 256
#define BSZ 32
#define ROWS (BSZ*NSEQ)   // 8192
#define KP 576            // padded proj K (514 -> 576 = 9*64)

typedef _Float16 half8_t __attribute__((ext_vector_type(8)));
typedef _Float16 half4_t __attribute__((ext_vector_type(4)));
typedef float f32x4 __attribute__((ext_vector_type(4)));

__device__ __forceinline__ void gload16(const _Float16* g, _Float16* l) {
    __builtin_amdgcn_global_load_lds(
        (const __attribute__((address_space(1))) unsigned int*)g,
        (__attribute__((address_space(3))) unsigned int*)l, 16, 0, 0);
}

// =============== fused prep: WcT transpose | WpT transpose | buildC ========
// WcT[c][h]  = f16(W[h*1536 + c])            c = t*512+o   [1536][512]
// WpT[o][k]  = f16(Wp[k][o]) zero-pad k>=514                [512][576]
// C16b[(b*256+n)][t*256+m] = f16( lut[adj[b,n,m]][t] + (n==m)*V[0][t] )
__global__ __launch_bounds__(256) void prep(
    const float* __restrict__ Wp, const float* __restrict__ W,
    const int* __restrict__ adj, const float* __restrict__ V,
    _Float16* __restrict__ WpT, _Float16* __restrict__ WcT,
    _Float16* __restrict__ C16b)
{
    __shared__ _Float16 ts[64][68];
    __shared__ _Float16 lutH[48];       // [r][t], r=0 zeroed
    __shared__ _Float16 V0h[3];
    const int blk = blockIdx.x, tid = threadIdx.x;

    if (blk < 192) {                        // ---- WcT (24 c-tiles x 8 h-tiles)
        int c0 = (blk % 24) * 64, h0 = (blk / 24) * 64;
        int r = tid >> 2, q = tid & 3;
        #pragma unroll
        for (int i = 0; i < 4; ++i) {
            float4 v = *(const float4*)&W[(size_t)(h0+r)*1536 + c0 + q*16 + i*4];
            ts[r][q*16+i*4+0] = (_Float16)v.x;
            ts[r][q*16+i*4+1] = (_Float16)v.y;
            ts[r][q*16+i*4+2] = (_Float16)v.z;
            ts[r][q*16+i*4+3] = (_Float16)v.w;
        }
        __syncthreads();
        _Float16* op = WcT + (size_t)(c0 + r)*512 + h0 + q*16;
        #pragma unroll
        for (int i = 0; i < 4; ++i) {
            half4_t o;
            #pragma unroll
            for (int j = 0; j < 4; ++j) o[j] = ts[q*16+i*4+j][r];
            *(half4_t*)(op + i*4) = o;
        }
    } else if (blk < 264) {                 // ---- WpT (9 k-tiles x 8 o-tiles)
        int sub = blk - 192;
        int k0 = (sub % 9) * 64, o0 = (sub / 9) * 64;
        int r = tid >> 2, q = tid & 3;
        int k = k0 + r;
        #pragma unroll
        for (int i = 0; i < 4; ++i) {
            float4 v = make_float4(0.f,0.f,0.f,0.f);
            if (k < 514) v = *(const float4*)&Wp[(size_t)k*HID + o0 + q*16 + i*4];
            ts[r][q*16+i*4+0] = (_Float16)v.x;
            ts[r][q*16+i*4+1] = (_Float16)v.y;
            ts[r][q*16+i*4+2] = (_Float16)v.z;
            ts[r][q*16+i*4+3] = (_Float16)v.w;
        }
        __syncthreads();
        _Float16* op = WpT + (size_t)(o0 + r)*KP + k0 + q*16;
        #pragma unroll
        for (int i = 0; i < 4; ++i) {
            half4_t o;
            #pragma unroll
            for (int j = 0; j < 4; ++j) o[j] = ts[q*16+i*4+j][r];
            *(half4_t*)(op + i*4) = o;
        }
    } else {                                // ---- C16b (128 blocks: 32 b x 4 n-tiles)
        if (tid < 48) { int r = tid/3; lutH[tid] = (_Float16)((r >= 1) ? V[tid] : 0.f); }
        if (tid < 3) V0h[tid] = (_Float16)V[tid];
        __syncthreads();
        int sub = blk - 264;
        int b = sub >> 2, nt = sub & 3;
        int w = tid >> 6, lane = tid & 63;
        // one wave per n-row: lanes cover m = lane*4 -> 512B coalesced bursts
        #pragma unroll
        for (int i = 0; i < 16; ++i) {
            int n = nt*64 + w*16 + i;
            int4 a4 = *(const int4*)(adj + ((size_t)(b*NSEQ + n))*NSEQ + lane*4);
            int av[4] = { a4.x, a4.y, a4.z, a4.w };
            size_t ob = ((size_t)(b*NSEQ + n))*768 + lane*4;
            #pragma unroll
            for (int t = 0; t < 3; ++t) {
                half4_t o;
                #pragma unroll
                for (int j = 0; j < 4; ++j) o[j] = lutH[av[j]*3 + t];
                if ((n >> 2) == lane) o[n & 3] = (_Float16)(o[n & 3] + V0h[t]);
                *(half4_t*)(C16b + ob + (size_t)t*256) = o;
            }
        }
    }
}

// ========= fused proj GEMM + LayerNorm + GELU -> Xh f16 [8192][512] =========
// BM=32, BN=512 (full row per block), K=576. 512 thr / 8 waves, wave tile 32x64.
// B (WpT) LDS double-buffered (2-phase drain schedule, proven); A read direct
// from cols/logits f32 global -> reg f16 (each (row,k) read exactly once).
__global__ __launch_bounds__(512) void proj_ln(
    const float* __restrict__ cols, const float* __restrict__ logits,
    const _Float16* __restrict__ WpT, const float* __restrict__ bp,
    const float* __restrict__ lg, const float* __restrict__ lb,
    _Float16* __restrict__ Xh)
{
    __shared__ _Float16 smem[2*32768];      // 2 x [512 col][64 k] f16 = 128KB
    __shared__ float redw[8][32][2];
    __shared__ float redf[32][2];
    const int tid = threadIdx.x;
    const int w = tid >> 6, lane = tid & 63;
    const int r16 = lane & 15, g4 = lane >> 4;
    const int row0 = blockIdx.x * 32;

    f32x4 acc[2][4] = {};   // [mi][ni]

    auto stage = [&](int kt, int bi) {       // 8 gload16 per wave, uniform
        _Float16* lb_ = smem + bi * 32768;
        #pragma unroll
        for (int l = 0; l < 8; ++l) {
            int gw = w * 512 + l * 64;
            int g  = gw + lane;
            int colr = g >> 3;
            int c    = (g & 7) ^ (colr & 7);
            gload16(WpT + (size_t)colr * KP + kt * 64 + c * 8, smem + bi*32768 + gw * 8);
            (void)lb_;
        }
    };

    auto compute = [&](int kt, int bi) {
        const _Float16* Bb = smem + bi * 32768;
        #pragma unroll
        for (int kh = 0; kh < 2; ++kh) {
            const int ks = g4 + kh * 4;
            const int k  = kt * 64 + ks * 8;
            half8_t a[2], b[4];
            #pragma unroll
            for (int mi = 0; mi < 2; ++mi) {
                int row = row0 + mi * 16 + r16;
                if (kt < 8) {
                    float4 f0 = *(const float4*)&cols[(size_t)row * 512 + k];
                    float4 f1 = *(const float4*)&cols[(size_t)row * 512 + k + 4];
                    a[mi][0]=(_Float16)f0.x; a[mi][1]=(_Float16)f0.y;
                    a[mi][2]=(_Float16)f0.z; a[mi][3]=(_Float16)f0.w;
                    a[mi][4]=(_Float16)f1.x; a[mi][5]=(_Float16)f1.y;
                    a[mi][6]=(_Float16)f1.z; a[mi][7]=(_Float16)f1.w;
                } else {
                    float l0 = 0.f, l1 = 0.f;
                    if (ks == 0) { l0 = logits[(size_t)row*2]; l1 = logits[(size_t)row*2+1]; }
                    a[mi][0]=(_Float16)l0; a[mi][1]=(_Float16)l1;
                    a[mi][2]=0; a[mi][3]=0; a[mi][4]=0; a[mi][5]=0; a[mi][6]=0; a[mi][7]=0;
                }
            }
            #pragma unroll
            for (int ni = 0; ni < 4; ++ni) {
                int col = w * 64 + ni * 16 + r16;
                b[ni] = *(const half8_t*)(Bb + col * 64 + ((ks ^ (col & 7)) * 8));
            }
            #pragma unroll
            for (int mi = 0; mi < 2; ++mi)
                #pragma unroll
                for (int ni = 0; ni < 4; ++ni)
                    acc[mi][ni] = __builtin_amdgcn_mfma_f32_16x16x32_f16(
                        a[mi], b[ni], acc[mi][ni], 0, 0, 0);
        }
    };

    stage(0, 0);
    int buf = 0;
    #pragma unroll 1
    for (int kt = 0; kt < 9; ++kt) {
        __syncthreads();                    // drains vmcnt(0): tile kt resident
        if (kt < 8) stage(kt + 1, buf ^ 1);
        compute(kt, buf);
        buf ^= 1;
    }
    __syncthreads();                        // all B reads done; smem reusable

    // ---- bias + LN partials.  C/D: col=lane&15(+16ni), row=(lane>>4)*4+q(+16mi)
    #pragma unroll
    for (int ni = 0; ni < 4; ++ni) {
        float bv = bp[w * 64 + ni * 16 + r16];
        #pragma unroll
        for (int mi = 0; mi < 2; ++mi)
            #pragma unroll
            for (int q = 0; q < 4; ++q) acc[mi][ni][q] += bv;
    }
    #pragma unroll
    for (int mi = 0; mi < 2; ++mi) {
        #pragma unroll
        for (int q = 0; q < 4; ++q) {
            float s = 0.f, s2 = 0.f;
            #pragma unroll
            for (int ni = 0; ni < 4; ++ni) {
                float v = acc[mi][ni][q];
                s += v; s2 += v * v;
            }
            #pragma unroll
            for (int msk = 1; msk < 16; msk <<= 1) {
                s  += __shfl_xor(s,  msk);
                s2 += __shfl_xor(s2, msk);
            }
            if (r16 == 0) {
                int row = mi * 16 + g4 * 4 + q;
                redw[w][row][0] = s;
                redw[w][row][1] = s2;
            }
        }
    }
    __syncthreads();
    if (tid < 64) {
        int row = tid >> 1, j = tid & 1;
        float v = 0.f;
        #pragma unroll
        for (int ww = 0; ww < 8; ++ww) v += redw[ww][row][j];
        redf[row][j] = v;
    }
    __syncthreads();

    // ---- LN + exact GELU, write to ep [32][520] f16, then linear copy out
    _Float16* ep = smem;
    #pragma unroll
    for (int mi = 0; mi < 2; ++mi) {
        #pragma unroll
        for (int q = 0; q < 4; ++q) {
            int row = mi * 16 + g4 * 4 + q;
            float mu = redf[row][0] * (1.f/512.f);
            float var = redf[row][1] * (1.f/512.f) - mu * mu;
            float rs = rsqrtf(var + 1e-5f);
            #pragma unroll
            for (int ni = 0; ni < 4; ++ni) {
                int col = w * 64 + ni * 16 + r16;
                float y = (acc[mi][ni][q] - mu) * rs * lg[col] + lb[col];
                y = 0.5f * y * (1.f + erff(y * 0.70710678118654752f));
                ep[row * 520 + col] = (_Float16)y;
            }
        }
    }
    __syncthreads();
    #pragma unroll
    for (int it = 0; it < 4; ++it) {
        int g = it * 512 + tid;
        int row = g >> 6, c8 = g & 63;
        *(half8_t*)(Xh + (size_t)(row0 + row) * 512 + c8 * 8) =
            *(const half8_t*)&ep[row * 520 + c8 * 8];
    }
}

// ====== unified 128x128 f16 MFMA GEMM, 512 thr / 8 waves (wave tile 64x32) ======
// A[M][KS], B[.][KS]. EPI: 1 = f16 transposed scatter -> YT[b][o][t*256+m] (Y-GEMM)
//                          2 = f32 out[r][512], B base per b = row0>>8 (agg-out)
// DEPTH-deep stage-after-free pipeline, counted vmcnt(4*(DEPTH-1)) in steady
// state; tail peels DEPTH-1 iterations with decreasing waits (vmcnt(4), vmcnt(0)).
template<int KS, int NKT, int DEPTH, int NB, int NBLK, int EPI>
__global__ __launch_bounds__(512) void gemm512(
    const _Float16* __restrict__ A, const _Float16* __restrict__ Bm,
    void* __restrict__ outv)
{
    __shared__ _Float16 smem[DEPTH * 2 * 8192];
    _Float16* As = smem;
    _Float16* Bs = smem + DEPTH * 8192;
    const int tid = threadIdx.x;
    const int w = tid >> 6, lane = tid & 63;
    // XCD-chunked swizzle (NB % 8 == 0)
    const int ell = blockIdx.x;
    const int s = (ell & 7) * (NB / 8) + (ell >> 3);
    const int row0 = (s / NBLK) * 128, col0 = (s % NBLK) * 128;
    const int wr = (w >> 2) * 64, wc = (w & 3) * 32;
    const _Float16* Ag = A + (size_t)row0 * KS;
    const _Float16* Bg = (EPI == 2)
        ? Bm + (size_t)(row0 >> 8) * 512 * KS + (size_t)col0 * KS
        : Bm + (size_t)col0 * KS;

    f32x4 acc[4][2] = {};

    // stage tile kt into buffer bi. LDS dest linear; global source pre-swizzled:
    // physical granule (row, c) holds logical (row, c ^ (row&7)).
    auto stage = [&](int kt, int bi) {
        const _Float16* ga = Ag + kt * 64;
        const _Float16* gb = Bg + kt * 64;
        _Float16* la = As + bi * 8192;
        _Float16* lb = Bs + bi * 8192;
        #pragma unroll
        for (int l = 0; l < 2; ++l) {
            int gw = w * 128 + l * 64;
            int g  = gw + lane;
            int row = g >> 3;
            int c   = (g & 7) ^ (row & 7);
            gload16(ga + (size_t)row * KS + c * 8, la + gw * 8);
        }
        #pragma unroll
        for (int l = 0; l < 2; ++l) {
            int gw = w * 128 + l * 64;
            int g  = gw + lane;
            int row = g >> 3;
            int c   = (g & 7) ^ (row & 7);
            gload16(gb + (size_t)row * KS + c * 8, lb + gw * 8);
        }
    };

    auto compute = [&](int bi) {
        const _Float16* Ab = As + bi * 8192;
        const _Float16* Bb = Bs + bi * 8192;
        const int r16 = lane & 15;
        #pragma unroll
        for (int kh = 0; kh < 2; ++kh) {
            const int ks = (lane >> 4) + kh * 4;
            half8_t a[4], b[2];
            #pragma unroll
            for (int mi = 0; mi < 4; ++mi) {
                int row = wr + mi * 16 + r16;
                a[mi] = *(const half8_t*)(Ab + row * 64 + ((ks ^ (row & 7)) * 8));
            }
            #pragma unroll
            for (int ni = 0; ni < 2; ++ni) {
                int col = wc + ni * 16 + r16;
                b[ni] = *(const half8_t*)(Bb + col * 64 + ((ks ^ (col & 7)) * 8));
            }
            #pragma unroll
            for (int mi = 0; mi < 4; ++mi)
                #pragma unroll
                for (int ni = 0; ni < 2; ++ni)
                    acc[mi][ni] = __builtin_amdgcn_mfma_f32_16x16x32_f16(
                        a[mi], b[ni], acc[mi][ni], 0, 0, 0);
        }
    };

    // prologue: fill all DEPTH buffers (4*DEPTH loads in flight per wave)
    #pragma unroll
    for (int i = 0; i < DEPTH; ++i) stage(i, i);

    int buf = 0;
    // steady state: counted wait retires exactly tile kt; never drains to 0.
    #pragma unroll 1
    for (int kt = 0; kt < NKT - (DEPTH - 1); ++kt) {
        if constexpr (DEPTH == 2) asm volatile("s_waitcnt vmcnt(4)" ::: "memory");
        else                      asm volatile("s_waitcnt vmcnt(8)" ::: "memory");
        __builtin_amdgcn_s_barrier();          // all waves: tile kt resident
        __builtin_amdgcn_s_setprio(1);
        compute(buf);
        __builtin_amdgcn_s_setprio(0);
        asm volatile("" ::: "memory");
        __builtin_amdgcn_s_barrier();          // all waves done reading buf
        if (kt + DEPTH < NKT) stage(kt + DEPTH, buf);
        ++buf; if (buf == DEPTH) buf = 0;
    }
    // tail: DEPTH-1 remaining tiles, decreasing counted waits (drain correctly)
    if constexpr (DEPTH == 3) {
        asm volatile("s_waitcnt vmcnt(4)" ::: "memory");
        __builtin_amdgcn_s_barrier();
        __builtin_amdgcn_s_setprio(1);
        compute(buf);
        __builtin_amdgcn_s_setprio(0);
        asm volatile("" ::: "memory");
        __builtin_amdgcn_s_barrier();
        ++buf; if (buf == DEPTH) buf = 0;
    }
    asm volatile("s_waitcnt vmcnt(0)" ::: "memory");
    __builtin_amdgcn_s_barrier();
    compute(buf);

    // C/D layout: col = lane&15, row = (lane>>4)*4 + q
    if constexpr (EPI == 2) {
        float* out = (float*)outv;
        #pragma unroll
        for (int mi = 0; mi < 4; ++mi) {
            int r = row0 + wr + mi * 16 + (lane >> 4) * 4;
            #pragma unroll
            for (int ni = 0; ni < 2; ++ni) {
                int cidx = col0 + wc + ni * 16 + (lane & 15);
                #pragma unroll
                for (int q = 0; q < 4; ++q)
                    out[(size_t)(r + q) * HID + cidx] = acc[mi][ni][q];
            }
        }
    } else {
        // transposed f16 scatter: YT[b][o0+c][t*256 + m0 + r]
        __syncthreads();                       // all compute done; reuse smem
        _Float16* ep = smem;                   // [128 c][136]
        #pragma unroll
        for (int mi = 0; mi < 4; ++mi) {
            int rb = wr + mi * 16 + (lane >> 4) * 4;
            #pragma unroll
            for (int ni = 0; ni < 2; ++ni) {
                int c = wc + ni * 16 + (lane & 15);
                half4_t h4;
                #pragma unroll
                for (int q = 0; q < 4; ++q) h4[q] = (_Float16)acc[mi][ni][q];
                *(half4_t*)&ep[c * 136 + rb] = h4;
            }
        }
        __syncthreads();
        const int b = row0 >> 8, m0 = row0 & 255, t = col0 >> 9, o0 = col0 & 511;
        _Float16* yb = (_Float16*)outv + ((size_t)b * 512 + o0) * 768 + (size_t)t * 256 + m0;
        #pragma unroll
        for (int it = 0; it < 4; ++it) {
            int g = it * 512 + tid;
            int c = g >> 4, m8 = g & 15;
            *(half8_t*)(yb + (size_t)c * 768 + m8 * 8) =
                *(const half8_t*)&ep[c * 136 + m8 * 8];
        }
    }
}

extern "C" void kernel_launch(void* const* d_in, const int* in_sizes, int n_in,
                              void* d_out, int out_size, void* d_ws, size_t ws_size,
                              hipStream_t stream)
{
    const float* cols   = (const float*)d_in[0];
    const float* logits = (const float*)d_in[1];
    const int*   adj    = (const int*)  d_in[2];
    const float* Wp     = (const float*)d_in[3];
    const float* bp     = (const float*)d_in[4];
    const float* lg     = (const float*)d_in[5];
    const float* lb     = (const float*)d_in[6];
    const float* W      = (const float*)d_in[7];
    const float* V      = (const float*)d_in[8];
    float* out  = (float*)d_out;

    char* p = (char*)d_ws;
    _Float16* Xh   = (_Float16*)p;  p += (size_t)ROWS*HID*2;          // 8.4 MB
    _Float16* WpT  = (_Float16*)p;  p += (size_t)HID*KP*2;            // 0.6 MB
    _Float16* WcT  = (_Float16*)p;  p += (size_t)1536*HID*2;          // 1.6 MB
    _Float16* C16b = (_Float16*)p;  p += (size_t)ROWS*768*2;          // 12.6 MB
    _Float16* YTb  = (_Float16*)p;  p += (size_t)BSZ*HID*768*2;       // 25.2 MB

    prep<<<392, 256, 0, stream>>>(Wp, W, adj, V, WpT, WcT, C16b);
    proj_ln<<<256, 512, 0, stream>>>(cols, logits, WpT, bp, lg, lb, Xh);
    gemm512<512, 8, 2, 768, 12, 1><<<768, 512, 0, stream>>>(Xh, WcT, YTb);
    gemm512<768, 12, 3, 256, 4, 2><<<256, 512, 0, stream>>>(C16b, YTb, out);
}

// Round 11
// 69.725 us; speedup vs baseline: 1.1091x; 1.1091x over previous
//
#include <hip/hip_runtime.h>
#include <math.h>

#define HID 512
#define NSEQ 256
#define BSZ 32
#define ROWS (BSZ*NSEQ)   // 8192
#define KP 576            // padded proj K (514 -> 576 = 9*64)

typedef _Float16 half8_t __attribute__((ext_vector_type(8)));
typedef _Float16 half4_t __attribute__((ext_vector_type(4)));
typedef float f32x4 __attribute__((ext_vector_type(4)));

__device__ __forceinline__ void gload16(const _Float16* g, _Float16* l) {
    __builtin_amdgcn_global_load_lds(
        (const __attribute__((address_space(1))) unsigned int*)g,
        (__attribute__((address_space(3))) unsigned int*)l, 16, 0, 0);
}

// =============== fused prep: cat_inp | WcT transpose | WpT transpose | buildC ========
// (identical to the round-9 verified version)
__global__ __launch_bounds__(256) void prep(
    const float* __restrict__ cols, const float* __restrict__ logits,
    const float* __restrict__ Wp, const float* __restrict__ W,
    const int* __restrict__ adj, const float* __restrict__ V,
    _Float16* __restrict__ Acat, _Float16* __restrict__ WpT,
    _Float16* __restrict__ WcT, _Float16* __restrict__ C16b)
{
    __shared__ _Float16 ts[64][68];
    __shared__ _Float16 lutH[48];       // [r][t], r=0 zeroed
    __shared__ _Float16 V0h[3];
    const int blk = blockIdx.x, tid = threadIdx.x;

    if (blk < 1024) {                       // ---- Acat: concat+cast, 8 rows/block
        int row0 = blk * 8;
        #pragma unroll
        for (int rr = 0; rr < 8; ++rr) {
            int row = row0 + rr;
            for (int k = tid; k < KP; k += 256) {
                float v = 0.f;
                if (k < 512) v = cols[(size_t)row*512 + k];
                else if (k < 514) v = logits[(size_t)row*2 + (k-512)];
                Acat[(size_t)row*KP + k] = (_Float16)v;
            }
        }
    } else if (blk < 1216) {                // ---- WcT (192 blocks: 24 c-tiles x 8 h-tiles)
        int sub = blk - 1024;
        int c0 = (sub % 24) * 64, h0 = (sub / 24) * 64;
        int r = tid >> 2, q = tid & 3;
        #pragma unroll
        for (int i = 0; i < 4; ++i) {
            float4 v = *(const float4*)&W[(size_t)(h0+r)*1536 + c0 + q*16 + i*4];
            ts[r][q*16+i*4+0] = (_Float16)v.x;
            ts[r][q*16+i*4+1] = (_Float16)v.y;
            ts[r][q*16+i*4+2] = (_Float16)v.z;
            ts[r][q*16+i*4+3] = (_Float16)v.w;
        }
        __syncthreads();
        _Float16* op = WcT + (size_t)(c0 + r)*512 + h0 + q*16;
        #pragma unroll
        for (int i = 0; i < 4; ++i) {
            half4_t o;
            #pragma unroll
            for (int j = 0; j < 4; ++j) o[j] = ts[q*16+i*4+j][r];
            *(half4_t*)(op + i*4) = o;
        }
    } else if (blk < 1288) {                // ---- WpT (72 blocks: 9 k-tiles x 8 o-tiles)
        int sub = blk - 1216;
        int k0 = (sub % 9) * 64, o0 = (sub / 9) * 64;
        int r = tid >> 2, q = tid & 3;
        int k = k0 + r;
        #pragma unroll
        for (int i = 0; i < 4; ++i) {
            float4 v = make_float4(0.f,0.f,0.f,0.f);
            if (k < 514) v = *(const float4*)&Wp[(size_t)k*HID + o0 + q*16 + i*4];
            ts[r][q*16+i*4+0] = (_Float16)v.x;
            ts[r][q*16+i*4+1] = (_Float16)v.y;
            ts[r][q*16+i*4+2] = (_Float16)v.z;
            ts[r][q*16+i*4+3] = (_Float16)v.w;
        }
        __syncthreads();
        _Float16* op = WpT + (size_t)(o0 + r)*KP + k0 + q*16;
        #pragma unroll
        for (int i = 0; i < 4; ++i) {
            half4_t o;
            #pragma unroll
            for (int j = 0; j < 4; ++j) o[j] = ts[q*16+i*4+j][r];
            *(half4_t*)(op + i*4) = o;
        }
    } else {                                // ---- C16b (128 blocks: 32 b x 4 n-tiles)
        if (tid < 48) { int r = tid/3; lutH[tid] = (_Float16)((r >= 1) ? V[tid] : 0.f); }
        if (tid < 3) V0h[tid] = (_Float16)V[tid];
        __syncthreads();
        int sub = blk - 1288;
        int b = sub >> 2, nt = sub & 3;
        int w = tid >> 6, lane = tid & 63;
        // one wave per n-row: lanes cover m = lane*4 -> 512B coalesced bursts
        #pragma unroll
        for (int i = 0; i < 16; ++i) {
            int n = nt*64 + w*16 + i;
            int4 a4 = *(const int4*)(adj + ((size_t)(b*NSEQ + n))*NSEQ + lane*4);
            int av[4] = { a4.x, a4.y, a4.z, a4.w };
            size_t ob = ((size_t)(b*NSEQ + n))*768 + lane*4;
            #pragma unroll
            for (int t = 0; t < 3; ++t) {
                half4_t o;
                #pragma unroll
                for (int j = 0; j < 4; ++j) o[j] = lutH[av[j]*3 + t];
                if ((n >> 2) == lane) o[n & 3] = (_Float16)(o[n & 3] + V0h[t]);
                *(half4_t*)(C16b + ob + (size_t)t*256) = o;
            }
        }
    }
}

// ========= fused proj GEMM + LayerNorm + GELU -> Xh f16 [8192][512] =========
// BM=32, BN=512 (full row per block), K=576=9x64. 512 thr / 8 waves, wave tile 32x64.
// BOTH A (Acat f16, 4KB/tile) and B (WpT, 64KB/tile) staged via gload16,
// DEPTH=2, counted vmcnt(9): per wave 8 B-gloads + 1 half-masked A-gload.
__global__ __launch_bounds__(512) void proj_ln(
    const _Float16* __restrict__ Acat, const _Float16* __restrict__ WpT,
    const float* __restrict__ bp, const float* __restrict__ lg,
    const float* __restrict__ lb, _Float16* __restrict__ Xh)
{
    __shared__ _Float16 Bsm[2*32768];       // 2 x [512 col][64 k] = 128KB
    __shared__ _Float16 Asm[2*2048];        // 2 x [32 row][64 k]  = 8KB
    __shared__ float redw[8][32][2];
    __shared__ float redf[32][2];
    const int tid = threadIdx.x;
    const int w = tid >> 6, lane = tid & 63;
    const int r16 = lane & 15, g4 = lane >> 4;
    const int row0 = blockIdx.x * 32;

    f32x4 acc[2][4] = {};   // [mi][ni]

    // stage tile kt into buffer bi: 9 gloads per wave (8 B + 1 A half-masked)
    auto stage = [&](int kt, int bi) {
        // A: 256 granules; wave w covers granules [w*32, w*32+32) with lanes<32
        if (lane < 32) {
            int g = w * 32 + lane;
            int row = g >> 3;
            int c   = (g & 7) ^ (row & 7);
            gload16(Acat + (size_t)(row0 + row) * KP + kt * 64 + c * 8,
                    Asm + bi * 2048 + (w * 32) * 8);
        }
        #pragma unroll
        for (int l = 0; l < 8; ++l) {
            int gw = w * 512 + l * 64;
            int g  = gw + lane;
            int colr = g >> 3;
            int c    = (g & 7) ^ (colr & 7);
            gload16(WpT + (size_t)colr * KP + kt * 64 + c * 8,
                    Bsm + bi * 32768 + gw * 8);
        }
    };

    auto compute = [&](int bi) {
        const _Float16* Ab = Asm + bi * 2048;
        const _Float16* Bb = Bsm + bi * 32768;
        #pragma unroll
        for (int kh = 0; kh < 2; ++kh) {
            const int ks = g4 + kh * 4;
            half8_t a[2], b[4];
            #pragma unroll
            for (int mi = 0; mi < 2; ++mi) {
                int row = mi * 16 + r16;
                a[mi] = *(const half8_t*)(Ab + row * 64 + ((ks ^ (row & 7)) * 8));
            }
            #pragma unroll
            for (int ni = 0; ni < 4; ++ni) {
                int col = w * 64 + ni * 16 + r16;
                b[ni] = *(const half8_t*)(Bb + col * 64 + ((ks ^ (col & 7)) * 8));
            }
            #pragma unroll
            for (int mi = 0; mi < 2; ++mi)
                #pragma unroll
                for (int ni = 0; ni < 4; ++ni)
                    acc[mi][ni] = __builtin_amdgcn_mfma_f32_16x16x32_f16(
                        a[mi], b[ni], acc[mi][ni], 0, 0, 0);
        }
    };

    stage(0, 0);
    stage(1, 1);
    int buf = 0;
    #pragma unroll 1
    for (int kt = 0; kt < 8; ++kt) {        // NKT=9, steady loop over first 8
        asm volatile("s_waitcnt vmcnt(9)" ::: "memory");   // tile kt's 9 retired
        __builtin_amdgcn_s_barrier();
        __builtin_amdgcn_s_setprio(1);
        compute(buf);
        __builtin_amdgcn_s_setprio(0);
        asm volatile("" ::: "memory");
        __builtin_amdgcn_s_barrier();
        if (kt + 2 < 9) stage(kt + 2, buf);
        buf ^= 1;
    }
    asm volatile("s_waitcnt vmcnt(0)" ::: "memory");
    __builtin_amdgcn_s_barrier();
    compute(buf);
    __syncthreads();                        // all LDS reads done; Bsm reusable

    // ---- bias + LN partials.  C/D: col=lane&15(+16ni), row=(lane>>4)*4+q(+16mi)
    #pragma unroll
    for (int ni = 0; ni < 4; ++ni) {
        float bv = bp[w * 64 + ni * 16 + r16];
        #pragma unroll
        for (int mi = 0; mi < 2; ++mi)
            #pragma unroll
            for (int q = 0; q < 4; ++q) acc[mi][ni][q] += bv;
    }
    #pragma unroll
    for (int mi = 0; mi < 2; ++mi) {
        #pragma unroll
        for (int q = 0; q < 4; ++q) {
            float s = 0.f, s2 = 0.f;
            #pragma unroll
            for (int ni = 0; ni < 4; ++ni) {
                float v = acc[mi][ni][q];
                s += v; s2 += v * v;
            }
            #pragma unroll
            for (int msk = 1; msk < 16; msk <<= 1) {
                s  += __shfl_xor(s,  msk);
                s2 += __shfl_xor(s2, msk);
            }
            if (r16 == 0) {
                int row = mi * 16 + g4 * 4 + q;
                redw[w][row][0] = s;
                redw[w][row][1] = s2;
            }
        }
    }
    __syncthreads();
    if (tid < 64) {
        int row = tid >> 1, j = tid & 1;
        float v = 0.f;
        #pragma unroll
        for (int ww = 0; ww < 8; ++ww) v += redw[ww][row][j];
        redf[row][j] = v;
    }
    __syncthreads();

    // ---- LN + exact GELU, write to ep [32][520] f16, then linear copy out
    _Float16* ep = Bsm;
    #pragma unroll
    for (int mi = 0; mi < 2; ++mi) {
        #pragma unroll
        for (int q = 0; q < 4; ++q) {
            int row = mi * 16 + g4 * 4 + q;
            float mu = redf[row][0] * (1.f/512.f);
            float var = redf[row][1] * (1.f/512.f) - mu * mu;
            float rs = rsqrtf(var + 1e-5f);
            #pragma unroll
            for (int ni = 0; ni < 4; ++ni) {
                int col = w * 64 + ni * 16 + r16;
                float y = (acc[mi][ni][q] - mu) * rs * lg[col] + lb[col];
                y = 0.5f * y * (1.f + erff(y * 0.70710678118654752f));
                ep[row * 520 + col] = (_Float16)y;
            }
        }
    }
    __syncthreads();
    #pragma unroll
    for (int it = 0; it < 4; ++it) {
        int g = it * 512 + tid;
        int row = g >> 6, c8 = g & 63;
        *(half8_t*)(Xh + (size_t)(row0 + row) * 512 + c8 * 8) =
            *(const half8_t*)&ep[row * 520 + c8 * 8];
    }
}

// ====== unified 128x128 f16 MFMA GEMM, 512 thr / 8 waves (wave tile 64x32) ======
// A[M][KS], B[.][KS]. EPI: 1 = f16 transposed scatter -> YT[b][o][t*256+m] (Y-GEMM)
//                          2 = f32 out[r][512], B base per b = row0>>8 (agg-out)
// DEPTH-deep stage-after-free pipeline, counted vmcnt(4*(DEPTH-1)) in steady
// state; tail peels DEPTH-1 iterations with decreasing waits (vmcnt(4), vmcnt(0)).
template<int KS, int NKT, int DEPTH, int NB, int NBLK, int EPI>
__global__ __launch_bounds__(512) void gemm512(
    const _Float16* __restrict__ A, const _Float16* __restrict__ Bm,
    void* __restrict__ outv)
{
    __shared__ _Float16 smem[DEPTH * 2 * 8192];
    _Float16* As = smem;
    _Float16* Bs = smem + DEPTH * 8192;
    const int tid = threadIdx.x;
    const int w = tid >> 6, lane = tid & 63;
    // XCD-chunked swizzle (NB % 8 == 0)
    const int ell = blockIdx.x;
    const int s = (ell & 7) * (NB / 8) + (ell >> 3);
    const int row0 = (s / NBLK) * 128, col0 = (s % NBLK) * 128;
    const int wr = (w >> 2) * 64, wc = (w & 3) * 32;
    const _Float16* Ag = A + (size_t)row0 * KS;
    const _Float16* Bg = (EPI == 2)
        ? Bm + (size_t)(row0 >> 8) * 512 * KS + (size_t)col0 * KS
        : Bm + (size_t)col0 * KS;

    f32x4 acc[4][2] = {};

    // stage tile kt into buffer bi. LDS dest linear; global source pre-swizzled:
    // physical granule (row, c) holds logical (row, c ^ (row&7)).
    auto stage = [&](int kt, int bi) {
        const _Float16* ga = Ag + kt * 64;
        const _Float16* gb = Bg + kt * 64;
        _Float16* la = As + bi * 8192;
        _Float16* lb = Bs + bi * 8192;
        #pragma unroll
        for (int l = 0; l < 2; ++l) {
            int gw = w * 128 + l * 64;
            int g  = gw + lane;
            int row = g >> 3;
            int c   = (g & 7) ^ (row & 7);
            gload16(ga + (size_t)row * KS + c * 8, la + gw * 8);
        }
        #pragma unroll
        for (int l = 0; l < 2; ++l) {
            int gw = w * 128 + l * 64;
            int g  = gw + lane;
            int row = g >> 3;
            int c   = (g & 7) ^ (row & 7);
            gload16(gb + (size_t)row * KS + c * 8, lb + gw * 8);
        }
    };

    auto compute = [&](int bi) {
        const _Float16* Ab = As + bi * 8192;
        const _Float16* Bb = Bs + bi * 8192;
        const int r16 = lane & 15;
        #pragma unroll
        for (int kh = 0; kh < 2; ++kh) {
            const int ks = (lane >> 4) + kh * 4;
            half8_t a[4], b[2];
            #pragma unroll
            for (int mi = 0; mi < 4; ++mi) {
                int row = wr + mi * 16 + r16;
                a[mi] = *(const half8_t*)(Ab + row * 64 + ((ks ^ (row & 7)) * 8));
            }
            #pragma unroll
            for (int ni = 0; ni < 2; ++ni) {
                int col = wc + ni * 16 + r16;
                b[ni] = *(const half8_t*)(Bb + col * 64 + ((ks ^ (col & 7)) * 8));
            }
            #pragma unroll
            for (int mi = 0; mi < 4; ++mi)
                #pragma unroll
                for (int ni = 0; ni < 2; ++ni)
                    acc[mi][ni] = __builtin_amdgcn_mfma_f32_16x16x32_f16(
                        a[mi], b[ni], acc[mi][ni], 0, 0, 0);
        }
    };

    // prologue: fill all DEPTH buffers (4*DEPTH loads in flight per wave)
    #pragma unroll
    for (int i = 0; i < DEPTH; ++i) stage(i, i);

    int buf = 0;
    // steady state: counted wait retires exactly tile kt; never drains to 0.
    #pragma unroll 1
    for (int kt = 0; kt < NKT - (DEPTH - 1); ++kt) {
        if constexpr (DEPTH == 2) asm volatile("s_waitcnt vmcnt(4)" ::: "memory");
        else                      asm volatile("s_waitcnt vmcnt(8)" ::: "memory");
        __builtin_amdgcn_s_barrier();          // all waves: tile kt resident
        __builtin_amdgcn_s_setprio(1);
        compute(buf);
        __builtin_amdgcn_s_setprio(0);
        asm volatile("" ::: "memory");
        __builtin_amdgcn_s_barrier();          // all waves done reading buf
        if (kt + DEPTH < NKT) stage(kt + DEPTH, buf);
        ++buf; if (buf == DEPTH) buf = 0;
    }
    // tail: DEPTH-1 remaining tiles, decreasing counted waits (drain correctly)
    if constexpr (DEPTH == 3) {
        asm volatile("s_waitcnt vmcnt(4)" ::: "memory");
        __builtin_amdgcn_s_barrier();
        __builtin_amdgcn_s_setprio(1);
        compute(buf);
        __builtin_amdgcn_s_setprio(0);
        asm volatile("" ::: "memory");
        __builtin_amdgcn_s_barrier();
        ++buf; if (buf == DEPTH) buf = 0;
    }
    asm volatile("s_waitcnt vmcnt(0)" ::: "memory");
    __builtin_amdgcn_s_barrier();
    compute(buf);

    // C/D layout: col = lane&15, row = (lane>>4)*4 + q
    if constexpr (EPI == 2) {
        float* out = (float*)outv;
        #pragma unroll
        for (int mi = 0; mi < 4; ++mi) {
            int r = row0 + wr + mi * 16 + (lane >> 4) * 4;
            #pragma unroll
            for (int ni = 0; ni < 2; ++ni) {
                int cidx = col0 + wc + ni * 16 + (lane & 15);
                #pragma unroll
                for (int q = 0; q < 4; ++q)
                    out[(size_t)(r + q) * HID + cidx] = acc[mi][ni][q];
            }
        }
    } else {
        // transposed f16 scatter: YT[b][o0+c][t*256 + m0 + r]
        __syncthreads();                       // all compute done; reuse smem
        _Float16* ep = smem;                   // [128 c][136]
        #pragma unroll
        for (int mi = 0; mi < 4; ++mi) {
            int rb = wr + mi * 16 + (lane >> 4) * 4;
            #pragma unroll
            for (int ni = 0; ni < 2; ++ni) {
                int c = wc + ni * 16 + (lane & 15);
                half4_t h4;
                #pragma unroll
                for (int q = 0; q < 4; ++q) h4[q] = (_Float16)acc[mi][ni][q];
                *(half4_t*)&ep[c * 136 + rb] = h4;
            }
        }
        __syncthreads();
        const int b = row0 >> 8, m0 = row0 & 255, t = col0 >> 9, o0 = col0 & 511;
        _Float16* yb = (_Float16*)outv + ((size_t)b * 512 + o0) * 768 + (size_t)t * 256 + m0;
        #pragma unroll
        for (int it = 0; it < 4; ++it) {
            int g = it * 512 + tid;
            int c = g >> 4, m8 = g & 15;
            *(half8_t*)(yb + (size_t)c * 768 + m8 * 8) =
                *(const half8_t*)&ep[c * 136 + m8 * 8];
        }
    }
}

extern "C" void kernel_launch(void* const* d_in, const int* in_sizes, int n_in,
                              void* d_out, int out_size, void* d_ws, size_t ws_size,
                              hipStream_t stream)
{
    const float* cols   = (const float*)d_in[0];
    const float* logits = (const float*)d_in[1];
    const int*   adj    = (const int*)  d_in[2];
    const float* Wp     = (const float*)d_in[3];
    const float* bp     = (const float*)d_in[4];
    const float* lg     = (const float*)d_in[5];
    const float* lb     = (const float*)d_in[6];
    const float* W      = (const float*)d_in[7];
    const float* V      = (const float*)d_in[8];
    float* out  = (float*)d_out;

    char* p = (char*)d_ws;
    _Float16* Xh   = (_Float16*)p;  p += (size_t)ROWS*HID*2;          // 8.4 MB
    _Float16* Acat = (_Float16*)p;  p += (size_t)ROWS*KP*2;           // 9.4 MB
    _Float16* WpT  = (_Float16*)p;  p += (size_t)HID*KP*2;            // 0.6 MB
    _Float16* WcT  = (_Float16*)p;  p += (size_t)1536*HID*2;          // 1.6 MB
    _Float16* C16b = (_Float16*)p;  p += (size_t)ROWS*768*2;          // 12.6 MB
    _Float16* YTb  = (_Float16*)p;  p += (size_t)BSZ*HID*768*2;       // 25.2 MB

    prep<<<1416, 256, 0, stream>>>(cols, logits, Wp, W, adj, V, Acat, WpT, WcT, C16b);
    proj_ln<<<256, 512, 0, stream>>>(Acat, WpT, bp, lg, lb, Xh);
    gemm512<512, 8, 2, 768, 12, 1><<<768, 512, 0, stream>>>(Xh, WcT, YTb);
    gemm512<768, 12, 3, 256, 4, 2><<<256, 512, 0, stream>>>(C16b, YTb, out);
}

// Round 12
// 68.584 us; speedup vs baseline: 1.1275x; 1.0166x over previous
//
#include <hip/hip_runtime.h>
#include <math.h>

#define HID 512
#define NSEQ 256
#define BSZ 32
#define ROWS (BSZ*NSEQ)   // 8192
#define KP 576            // padded proj K (514 -> 576 = 9*64)

typedef _Float16 half8_t __attribute__((ext_vector_type(8)));
typedef _Float16 half4_t __attribute__((ext_vector_type(4)));
typedef float f32x4 __attribute__((ext_vector_type(4)));

__device__ __forceinline__ void gload16(const _Float16* g, _Float16* l) {
    __builtin_amdgcn_global_load_lds(
        (const __attribute__((address_space(1))) unsigned int*)g,
        (__attribute__((address_space(3))) unsigned int*)l, 16, 0, 0);
}

// =============== fused prep: cat_inp | WcT transpose | WpT transpose | buildC ========
// (round-9 verified version)
__global__ __launch_bounds__(256) void prep(
    const float* __restrict__ cols, const float* __restrict__ logits,
    const float* __restrict__ Wp, const float* __restrict__ W,
    const int* __restrict__ adj, const float* __restrict__ V,
    _Float16* __restrict__ Acat, _Float16* __restrict__ WpT,
    _Float16* __restrict__ WcT, _Float16* __restrict__ C16b)
{
    __shared__ _Float16 ts[64][68];
    __shared__ _Float16 lutH[48];       // [r][t], r=0 zeroed
    __shared__ _Float16 V0h[3];
    const int blk = blockIdx.x, tid = threadIdx.x;

    if (blk < 1024) {                       // ---- Acat: concat+cast, 8 rows/block
        int row0 = blk * 8;
        #pragma unroll
        for (int rr = 0; rr < 8; ++rr) {
            int row = row0 + rr;
            for (int k = tid; k < KP; k += 256) {
                float v = 0.f;
                if (k < 512) v = cols[(size_t)row*512 + k];
                else if (k < 514) v = logits[(size_t)row*2 + (k-512)];
                Acat[(size_t)row*KP + k] = (_Float16)v;
            }
        }
    } else if (blk < 1216) {                // ---- WcT (192 blocks: 24 c-tiles x 8 h-tiles)
        int sub = blk - 1024;
        int c0 = (sub % 24) * 64, h0 = (sub / 24) * 64;
        int r = tid >> 2, q = tid & 3;
        #pragma unroll
        for (int i = 0; i < 4; ++i) {
            float4 v = *(const float4*)&W[(size_t)(h0+r)*1536 + c0 + q*16 + i*4];
            ts[r][q*16+i*4+0] = (_Float16)v.x;
            ts[r][q*16+i*4+1] = (_Float16)v.y;
            ts[r][q*16+i*4+2] = (_Float16)v.z;
            ts[r][q*16+i*4+3] = (_Float16)v.w;
        }
        __syncthreads();
        _Float16* op = WcT + (size_t)(c0 + r)*512 + h0 + q*16;
        #pragma unroll
        for (int i = 0; i < 4; ++i) {
            half4_t o;
            #pragma unroll
            for (int j = 0; j < 4; ++j) o[j] = ts[q*16+i*4+j][r];
            *(half4_t*)(op + i*4) = o;
        }
    } else if (blk < 1288) {                // ---- WpT (72 blocks: 9 k-tiles x 8 o-tiles)
        int sub = blk - 1216;
        int k0 = (sub % 9) * 64, o0 = (sub / 9) * 64;
        int r = tid >> 2, q = tid & 3;
        int k = k0 + r;
        #pragma unroll
        for (int i = 0; i < 4; ++i) {
            float4 v = make_float4(0.f,0.f,0.f,0.f);
            if (k < 514) v = *(const float4*)&Wp[(size_t)k*HID + o0 + q*16 + i*4];
            ts[r][q*16+i*4+0] = (_Float16)v.x;
            ts[r][q*16+i*4+1] = (_Float16)v.y;
            ts[r][q*16+i*4+2] = (_Float16)v.z;
            ts[r][q*16+i*4+3] = (_Float16)v.w;
        }
        __syncthreads();
        _Float16* op = WpT + (size_t)(o0 + r)*KP + k0 + q*16;
        #pragma unroll
        for (int i = 0; i < 4; ++i) {
            half4_t o;
            #pragma unroll
            for (int j = 0; j < 4; ++j) o[j] = ts[q*16+i*4+j][r];
            *(half4_t*)(op + i*4) = o;
        }
    } else {                                // ---- C16b (128 blocks: 32 b x 4 n-tiles)
        if (tid < 48) { int r = tid/3; lutH[tid] = (_Float16)((r >= 1) ? V[tid] : 0.f); }
        if (tid < 3) V0h[tid] = (_Float16)V[tid];
        __syncthreads();
        int sub = blk - 1288;
        int b = sub >> 2, nt = sub & 3;
        int w = tid >> 6, lane = tid & 63;
        // one wave per n-row: lanes cover m = lane*4 -> 512B coalesced bursts
        #pragma unroll
        for (int i = 0; i < 16; ++i) {
            int n = nt*64 + w*16 + i;
            int4 a4 = *(const int4*)(adj + ((size_t)(b*NSEQ + n))*NSEQ + lane*4);
            int av[4] = { a4.x, a4.y, a4.z, a4.w };
            size_t ob = ((size_t)(b*NSEQ + n))*768 + lane*4;
            #pragma unroll
            for (int t = 0; t < 3; ++t) {
                half4_t o;
                #pragma unroll
                for (int j = 0; j < 4; ++j) o[j] = lutH[av[j]*3 + t];
                if ((n >> 2) == lane) o[n & 3] = (_Float16)(o[n & 3] + V0h[t]);
                *(half4_t*)(C16b + ob + (size_t)t*256) = o;
            }
        }
    }
}

// ====== 128x128 f16 MFMA GEMM, 512 thr / 8 waves (wave tile 64x32) ======
// A[M][KS], B[.][KS]. EPI: 0 = f16 row-major out[r][512] + bias (proj)
//                          1 = f16 transposed scatter -> YT[b][o][t*256+m] (Y-GEMM)
// DEPTH-deep stage-after-free pipeline, counted vmcnt(4*(DEPTH-1)) in steady
// state; tail peels DEPTH-1 iterations with decreasing waits (vmcnt(4), vmcnt(0)).
template<int KS, int NKT, int DEPTH, int NB, int NBLK, int EPI>
__global__ __launch_bounds__(512) void gemm512(
    const _Float16* __restrict__ A, const _Float16* __restrict__ Bm,
    const float* __restrict__ bias, void* __restrict__ outv)
{
    __shared__ _Float16 smem[DEPTH * 2 * 8192];
    _Float16* As = smem;
    _Float16* Bs = smem + DEPTH * 8192;
    const int tid = threadIdx.x;
    const int w = tid >> 6, lane = tid & 63;
    // XCD-chunked swizzle (NB % 8 == 0)
    const int ell = blockIdx.x;
    const int s = (ell & 7) * (NB / 8) + (ell >> 3);
    const int row0 = (s / NBLK) * 128, col0 = (s % NBLK) * 128;
    const int wr = (w >> 2) * 64, wc = (w & 3) * 32;
    const _Float16* Ag = A + (size_t)row0 * KS;
    const _Float16* Bg = Bm + (size_t)col0 * KS;

    f32x4 acc[4][2] = {};

    // stage tile kt into buffer bi. LDS dest linear; global source pre-swizzled:
    // physical granule (row, c) holds logical (row, c ^ (row&7)).
    auto stage = [&](int kt, int bi) {
        const _Float16* ga = Ag + kt * 64;
        const _Float16* gb = Bg + kt * 64;
        _Float16* la = As + bi * 8192;
        _Float16* lb = Bs + bi * 8192;
        #pragma unroll
        for (int l = 0; l < 2; ++l) {
            int gw = w * 128 + l * 64;
            int g  = gw + lane;
            int row = g >> 3;
            int c   = (g & 7) ^ (row & 7);
            gload16(ga + (size_t)row * KS + c * 8, la + gw * 8);
        }
        #pragma unroll
        for (int l = 0; l < 2; ++l) {
            int gw = w * 128 + l * 64;
            int g  = gw + lane;
            int row = g >> 3;
            int c   = (g & 7) ^ (row & 7);
            gload16(gb + (size_t)row * KS + c * 8, lb + gw * 8);
        }
    };

    auto compute = [&](int bi) {
        const _Float16* Ab = As + bi * 8192;
        const _Float16* Bb = Bs + bi * 8192;
        const int r16 = lane & 15;
        #pragma unroll
        for (int kh = 0; kh < 2; ++kh) {
            const int ks = (lane >> 4) + kh * 4;
            half8_t a[4], b[2];
            #pragma unroll
            for (int mi = 0; mi < 4; ++mi) {
                int row = wr + mi * 16 + r16;
                a[mi] = *(const half8_t*)(Ab + row * 64 + ((ks ^ (row & 7)) * 8));
            }
            #pragma unroll
            for (int ni = 0; ni < 2; ++ni) {
                int col = wc + ni * 16 + r16;
                b[ni] = *(const half8_t*)(Bb + col * 64 + ((ks ^ (col & 7)) * 8));
            }
            #pragma unroll
            for (int mi = 0; mi < 4; ++mi)
                #pragma unroll
                for (int ni = 0; ni < 2; ++ni)
                    acc[mi][ni] = __builtin_amdgcn_mfma_f32_16x16x32_f16(
                        a[mi], b[ni], acc[mi][ni], 0, 0, 0);
        }
    };

    // prologue: fill all DEPTH buffers (4*DEPTH loads in flight per wave)
    #pragma unroll
    for (int i = 0; i < DEPTH; ++i) stage(i, i);

    int buf = 0;
    // steady state: counted wait retires exactly tile kt; never drains to 0.
    #pragma unroll 1
    for (int kt = 0; kt < NKT - (DEPTH - 1); ++kt) {
        if constexpr (DEPTH == 2) asm volatile("s_waitcnt vmcnt(4)" ::: "memory");
        else                      asm volatile("s_waitcnt vmcnt(8)" ::: "memory");
        __builtin_amdgcn_s_barrier();          // all waves: tile kt resident
        __builtin_amdgcn_s_setprio(1);
        compute(buf);
        __builtin_amdgcn_s_setprio(0);
        asm volatile("" ::: "memory");
        __builtin_amdgcn_s_barrier();          // all waves done reading buf
        if (kt + DEPTH < NKT) stage(kt + DEPTH, buf);
        ++buf; if (buf == DEPTH) buf = 0;
    }
    // tail: DEPTH-1 remaining tiles, decreasing counted waits (drain correctly)
    if constexpr (DEPTH == 3) {
        asm volatile("s_waitcnt vmcnt(4)" ::: "memory");
        __builtin_amdgcn_s_barrier();
        __builtin_amdgcn_s_setprio(1);
        compute(buf);
        __builtin_amdgcn_s_setprio(0);
        asm volatile("" ::: "memory");
        __builtin_amdgcn_s_barrier();
        ++buf; if (buf == DEPTH) buf = 0;
    }
    asm volatile("s_waitcnt vmcnt(0)" ::: "memory");
    __builtin_amdgcn_s_barrier();
    compute(buf);

    // C/D layout: col = lane&15, row = (lane>>4)*4 + q
    if constexpr (EPI == 0) {
        // f16 row-major + bias, LDS-repacked to 256B bursts
        __syncthreads();                       // all compute done; reuse smem
        _Float16* ep = smem;                   // [128 r][136]
        #pragma unroll
        for (int mi = 0; mi < 4; ++mi) {
            int rb = wr + mi * 16 + (lane >> 4) * 4;
            #pragma unroll
            for (int ni = 0; ni < 2; ++ni) {
                int c = wc + ni * 16 + (lane & 15);
                float bv = bias[col0 + c];
                #pragma unroll
                for (int q = 0; q < 4; ++q)
                    ep[(rb + q) * 136 + c] = (_Float16)(acc[mi][ni][q] + bv);
            }
        }
        __syncthreads();
        _Float16* ob = (_Float16*)outv + (size_t)row0 * HID + col0;
        #pragma unroll
        for (int it = 0; it < 4; ++it) {
            int g = it * 512 + tid;
            int r = g >> 4, c8 = g & 15;
            *(half8_t*)(ob + (size_t)r * HID + c8 * 8) =
                *(const half8_t*)&ep[r * 136 + c8 * 8];
        }
    } else {
        // transposed f16 scatter: YT[b][o0+c][t*256 + m0 + r]
        __syncthreads();                       // all compute done; reuse smem
        _Float16* ep = smem;                   // [128 c][136]
        #pragma unroll
        for (int mi = 0; mi < 4; ++mi) {
            int rb = wr + mi * 16 + (lane >> 4) * 4;
            #pragma unroll
            for (int ni = 0; ni < 2; ++ni) {
                int c = wc + ni * 16 + (lane & 15);
                half4_t h4;
                #pragma unroll
                for (int q = 0; q < 4; ++q) h4[q] = (_Float16)acc[mi][ni][q];
                *(half4_t*)&ep[c * 136 + rb] = h4;
            }
        }
        __syncthreads();
        const int b = row0 >> 8, m0 = row0 & 255, t = col0 >> 9, o0 = col0 & 511;
        _Float16* yb = (_Float16*)outv + ((size_t)b * 512 + o0) * 768 + (size_t)t * 256 + m0;
        #pragma unroll
        for (int it = 0; it < 4; ++it) {
            int g = it * 512 + tid;
            int c = g >> 4, m8 = g & 15;
            *(half8_t*)(yb + (size_t)c * 768 + m8 * 8) =
                *(const half8_t*)&ep[c * 136 + m8 * 8];
        }
    }
}

// ====== agg-out: out[b*256+n][col] = C16b[b] @ YTb[b], BM=256 x BN=64, K=768 ======
// Grid 256 = 32 b x 8 col-panels. Each YTb/C16b byte read exactly once.
// 8 waves (4 row x 2 col), wave tile 64x32. 5 gloads/wave/tile (4 A + 1 B).
// DEPTH=3: steady vmcnt(10), tail vmcnt(5), vmcnt(0).
__global__ __launch_bounds__(512) void aggout(
    const _Float16* __restrict__ C16b, const _Float16* __restrict__ YTb,
    float* __restrict__ out)
{
    __shared__ _Float16 smem[61440];        // 3 x (A 16384 + B 4096) f16 = 120KB
    _Float16* As = smem;                    // 3 x 16384
    _Float16* Bs = smem + 49152;            // 3 x 4096
    const int tid = threadIdx.x;
    const int w = tid >> 6, lane = tid & 63;
    const int ell = blockIdx.x;
    const int s = (ell & 7) * 32 + (ell >> 3);       // XCD-chunked swizzle
    const int b = s >> 3, col0 = (s & 7) * 64;
    const int wr = (w >> 1) * 64, wc = (w & 1) * 32;
    const _Float16* Ag = C16b + (size_t)b * NSEQ * 768;
    const _Float16* Bg = YTb + ((size_t)b * 512 + col0) * 768;

    f32x4 acc[4][2] = {};

    auto stage = [&](int kt, int bi) {
        const _Float16* ga = Ag + kt * 64;
        const _Float16* gb = Bg + kt * 64;
        _Float16* la = As + bi * 16384;
        _Float16* lb = Bs + bi * 4096;
        #pragma unroll
        for (int l = 0; l < 4; ++l) {        // A: 256 rows x 64 k = 2048 granules
            int gw = w * 256 + l * 64;
            int g  = gw + lane;
            int row = g >> 3;
            int c   = (g & 7) ^ (row & 7);
            gload16(ga + (size_t)row * 768 + c * 8, la + gw * 8);
        }
        {                                    // B: 64 rows x 64 k = 512 granules
            int gw = w * 64;
            int g  = gw + lane;
            int row = g >> 3;
            int c   = (g & 7) ^ (row & 7);
            gload16(gb + (size_t)row * 768 + c * 8, lb + gw * 8);
        }
    };

    auto compute = [&](int bi) {
        const _Float16* Ab = As + bi * 16384;
        const _Float16* Bb = Bs + bi * 4096;
        const int r16 = lane & 15;
        #pragma unroll
        for (int kh = 0; kh < 2; ++kh) {
            const int ks = (lane >> 4) + kh * 4;
            half8_t a[4], bfr[2];
            #pragma unroll
            for (int mi = 0; mi < 4; ++mi) {
                int row = wr + mi * 16 + r16;
                a[mi] = *(const half8_t*)(Ab + row * 64 + ((ks ^ (row & 7)) * 8));
            }
            #pragma unroll
            for (int ni = 0; ni < 2; ++ni) {
                int col = wc + ni * 16 + r16;
                bfr[ni] = *(const half8_t*)(Bb + col * 64 + ((ks ^ (col & 7)) * 8));
            }
            #pragma unroll
            for (int mi = 0; mi < 4; ++mi)
                #pragma unroll
                for (int ni = 0; ni < 2; ++ni)
                    acc[mi][ni] = __builtin_amdgcn_mfma_f32_16x16x32_f16(
                        a[mi], bfr[ni], acc[mi][ni], 0, 0, 0);
        }
    };

    stage(0, 0); stage(1, 1); stage(2, 2);   // 15 gloads/wave in flight
    int buf = 0;
    #pragma unroll 1
    for (int kt = 0; kt < 10; ++kt) {        // NKT=12, steady over first 10
        asm volatile("s_waitcnt vmcnt(10)" ::: "memory");  // tile kt's 5 retired
        __builtin_amdgcn_s_barrier();
        __builtin_amdgcn_s_setprio(1);
        compute(buf);
        __builtin_amdgcn_s_setprio(0);
        asm volatile("" ::: "memory");
        __builtin_amdgcn_s_barrier();
        if (kt + 3 < 12) stage(kt + 3, buf);
        ++buf; if (buf == 3) buf = 0;
    }
    asm volatile("s_waitcnt vmcnt(5)" ::: "memory");
    __builtin_amdgcn_s_barrier();
    __builtin_amdgcn_s_setprio(1);
    compute(buf);
    __builtin_amdgcn_s_setprio(0);
    asm volatile("" ::: "memory");
    __builtin_amdgcn_s_barrier();
    ++buf; if (buf == 3) buf = 0;
    asm volatile("s_waitcnt vmcnt(0)" ::: "memory");
    __builtin_amdgcn_s_barrier();
    compute(buf);

    // C/D layout: col = lane&15, row = (lane>>4)*4 + q
    #pragma unroll
    for (int mi = 0; mi < 4; ++mi) {
        int r = b * NSEQ + wr + mi * 16 + (lane >> 4) * 4;
        #pragma unroll
        for (int ni = 0; ni < 2; ++ni) {
            int cidx = col0 + wc + ni * 16 + (lane & 15);
            #pragma unroll
            for (int q = 0; q < 4; ++q)
                out[(size_t)(r + q) * HID + cidx] = acc[mi][ni][q];
        }
    }
}

// ------- LayerNorm + exact GELU, IN-PLACE on f16 [row][512] (block = row) -------
__global__ __launch_bounds__(256) void ln_gelu_ip(_Float16* __restrict__ h,
    const float* __restrict__ g, const float* __restrict__ bb)
{
    int row = blockIdx.x;
    int tid = threadIdx.x;
    float v0 = (float)h[(size_t)row*512 + tid];
    float v1 = (float)h[(size_t)row*512 + 256 + tid];
    __shared__ float red[4];
    int wid = tid >> 6, lane = tid & 63;

    float s = v0 + v1;
    #pragma unroll
    for (int off = 32; off; off >>= 1) s += __shfl_down(s, off);
    if (lane == 0) red[wid] = s;
    __syncthreads();
    float mu = (red[0]+red[1]+red[2]+red[3]) * (1.f/512.f);
    __syncthreads();

    float d0 = v0 - mu, d1 = v1 - mu;
    float q = d0*d0 + d1*d1;
    #pragma unroll
    for (int off = 32; off; off >>= 1) q += __shfl_down(q, off);
    if (lane == 0) red[wid] = q;
    __syncthreads();
    float var = (red[0]+red[1]+red[2]+red[3]) * (1.f/512.f);
    float rs = rsqrtf(var + 1e-5f);

    float y0 = d0*rs*g[tid] + bb[tid];
    float y1 = d1*rs*g[tid+256] + bb[tid+256];
    y0 = 0.5f*y0*(1.f + erff(y0*0.70710678118654752f));
    y1 = 0.5f*y1*(1.f + erff(y1*0.70710678118654752f));
    h[(size_t)row*512 + tid]       = (_Float16)y0;
    h[(size_t)row*512 + 256 + tid] = (_Float16)y1;
}

extern "C" void kernel_launch(void* const* d_in, const int* in_sizes, int n_in,
                              void* d_out, int out_size, void* d_ws, size_t ws_size,
                              hipStream_t stream)
{
    const float* cols   = (const float*)d_in[0];
    const float* logits = (const float*)d_in[1];
    const int*   adj    = (const int*)  d_in[2];
    const float* Wp     = (const float*)d_in[3];
    const float* bp     = (const float*)d_in[4];
    const float* lg     = (const float*)d_in[5];
    const float* lb     = (const float*)d_in[6];
    const float* W      = (const float*)d_in[7];
    const float* V      = (const float*)d_in[8];
    float* out  = (float*)d_out;

    char* p = (char*)d_ws;
    _Float16* Xh   = (_Float16*)p;  p += (size_t)ROWS*HID*2;          // 8.4 MB
    _Float16* Acat = (_Float16*)p;  p += (size_t)ROWS*KP*2;           // 9.4 MB
    _Float16* WpT  = (_Float16*)p;  p += (size_t)HID*KP*2;            // 0.6 MB
    _Float16* WcT  = (_Float16*)p;  p += (size_t)1536*HID*2;          // 1.6 MB
    _Float16* C16b = (_Float16*)p;  p += (size_t)ROWS*768*2;          // 12.6 MB
    _Float16* YTb  = (_Float16*)p;  p += (size_t)BSZ*HID*768*2;       // 25.2 MB

    prep<<<1416, 256, 0, stream>>>(cols, logits, Wp, W, adj, V, Acat, WpT, WcT, C16b);
    gemm512<KP, 9, 3, 256, 4, 0><<<256, 512, 0, stream>>>(Acat, WpT, bp, Xh);
    ln_gelu_ip<<<ROWS, 256, 0, stream>>>(Xh, lg, lb);
    gemm512<512, 8, 2, 768, 12, 1><<<768, 512, 0, stream>>>(Xh, WcT, nullptr, YTb);
    aggout<<<256, 512, 0, stream>>>(C16b, YTb, out);
}

// Round 13
// 64.904 us; speedup vs baseline: 1.1915x; 1.0567x over previous
//
#include <hip/hip_runtime.h>
#include <math.h>

#define HID 512
#define NSEQ 256
#define BSZ 32
#define ROWS (BSZ*NSEQ)   // 8192
#define KP 576            // padded proj K (514 -> 576 = 9*64)

typedef _Float16 half8_t __attribute__((ext_vector_type(8)));
typedef _Float16 half4_t __attribute__((ext_vector_type(4)));
typedef float f32x4 __attribute__((ext_vector_type(4)));
typedef float f32x8 __attribute__((ext_vector_type(8)));

__device__ __forceinline__ void gload16(const _Float16* g, _Float16* l) {
    __builtin_amdgcn_global_load_lds(
        (const __attribute__((address_space(1))) unsigned int*)g,
        (__attribute__((address_space(3))) unsigned int*)l, 16, 0, 0);
}
__device__ __forceinline__ void gload16f(const float* g, float* l) {
    __builtin_amdgcn_global_load_lds(
        (const __attribute__((address_space(1))) unsigned int*)g,
        (__attribute__((address_space(3))) unsigned int*)l, 16, 0, 0);
}

// =============== fused prep: WcT | WpT | C16b (round-10 verified, Acat dropped) =====
__global__ __launch_bounds__(256) void prep(
    const float* __restrict__ Wp, const float* __restrict__ W,
    const int* __restrict__ adj, const float* __restrict__ V,
    _Float16* __restrict__ WpT, _Float16* __restrict__ WcT,
    _Float16* __restrict__ C16b)
{
    __shared__ _Float16 ts[64][68];
    __shared__ _Float16 lutH[48];       // [r][t], r=0 zeroed
    __shared__ _Float16 V0h[3];
    const int blk = blockIdx.x, tid = threadIdx.x;

    if (blk < 192) {                        // ---- WcT (24 c-tiles x 8 h-tiles)
        int c0 = (blk % 24) * 64, h0 = (blk / 24) * 64;
        int r = tid >> 2, q = tid & 3;
        #pragma unroll
        for (int i = 0; i < 4; ++i) {
            float4 v = *(const float4*)&W[(size_t)(h0+r)*1536 + c0 + q*16 + i*4];
            ts[r][q*16+i*4+0] = (_Float16)v.x;
            ts[r][q*16+i*4+1] = (_Float16)v.y;
            ts[r][q*16+i*4+2] = (_Float16)v.z;
            ts[r][q*16+i*4+3] = (_Float16)v.w;
        }
        __syncthreads();
        _Float16* op = WcT + (size_t)(c0 + r)*512 + h0 + q*16;
        #pragma unroll
        for (int i = 0; i < 4; ++i) {
            half4_t o;
            #pragma unroll
            for (int j = 0; j < 4; ++j) o[j] = ts[q*16+i*4+j][r];
            *(half4_t*)(op + i*4) = o;
        }
    } else if (blk < 264) {                 // ---- WpT (9 k-tiles x 8 o-tiles)
        int sub = blk - 192;
        int k0 = (sub % 9) * 64, o0 = (sub / 9) * 64;
        int r = tid >> 2, q = tid & 3;
        int k = k0 + r;
        #pragma unroll
        for (int i = 0; i < 4; ++i) {
            float4 v = make_float4(0.f,0.f,0.f,0.f);
            if (k < 514) v = *(const float4*)&Wp[(size_t)k*HID + o0 + q*16 + i*4];
            ts[r][q*16+i*4+0] = (_Float16)v.x;
            ts[r][q*16+i*4+1] = (_Float16)v.y;
            ts[r][q*16+i*4+2] = (_Float16)v.z;
            ts[r][q*16+i*4+3] = (_Float16)v.w;
        }
        __syncthreads();
        _Float16* op = WpT + (size_t)(o0 + r)*KP + k0 + q*16;
        #pragma unroll
        for (int i = 0; i < 4; ++i) {
            half4_t o;
            #pragma unroll
            for (int j = 0; j < 4; ++j) o[j] = ts[q*16+i*4+j][r];
            *(half4_t*)(op + i*4) = o;
        }
    } else {                                // ---- C16b (128 blocks: 32 b x 4 n-tiles)
        if (tid < 48) { int r = tid/3; lutH[tid] = (_Float16)((r >= 1) ? V[tid] : 0.f); }
        if (tid < 3) V0h[tid] = (_Float16)V[tid];
        __syncthreads();
        int sub = blk - 264;
        int b = sub >> 2, nt = sub & 3;
        int w = tid >> 6, lane = tid & 63;
        #pragma unroll
        for (int i = 0; i < 16; ++i) {
            int n = nt*64 + w*16 + i;
            int4 a4 = *(const int4*)(adj + ((size_t)(b*NSEQ + n))*NSEQ + lane*4);
            int av[4] = { a4.x, a4.y, a4.z, a4.w };
            size_t ob = ((size_t)(b*NSEQ + n))*768 + lane*4;
            #pragma unroll
            for (int t = 0; t < 3; ++t) {
                half4_t o;
                #pragma unroll
                for (int j = 0; j < 4; ++j) o[j] = lutH[av[j]*3 + t];
                if ((n >> 2) == lane) o[n & 3] = (_Float16)(o[n & 3] + V0h[t]);
                *(half4_t*)(C16b + ob + (size_t)t*256) = o;
            }
        }
    }
}

// ========= projx: Xh[r][o] = f16( concat(cols,logits)[r] @ WpT^T + bp ) =========
// BM=64, BN=128. Grid 512 (128 row x 4 col panels). 8 waves, wave tile 32x32.
// A staged DIRECTLY from f32 cols via gload16f (32B-unit XOR swizzle), converted
// f32->f16 (RNE) at ds_read. Logits handled as 9th K-phase from small LDS tile.
// DEPTH=2 counted pipeline: steady vmcnt(4); tail vmcnt(2), vmcnt(0).
__global__ __launch_bounds__(512) void projx(
    const float* __restrict__ cols, const float* __restrict__ logits,
    const _Float16* __restrict__ WpT, const float* __restrict__ bp,
    _Float16* __restrict__ Xh)
{
    __shared__ float    Asf[2*4096];    // 2 x [64 row][64 k] f32 = 32KB
    __shared__ _Float16 Bsm[2*8192];    // 2 x [128 col][64 k] f16 = 32KB
    __shared__ _Float16 Lt[4096];       // logits A-tile [64][64] f16 = 8KB
    const int tid = threadIdx.x;
    const int w = tid >> 6, lane = tid & 63;
    const int r16 = lane & 15, g4 = lane >> 4;
    const int ell = blockIdx.x;
    const int s = (ell & 7) * 64 + (ell >> 3);       // XCD-chunked swizzle
    const int row0 = (s >> 2) * 64, col0 = (s & 3) * 128;
    const int wr = (w >> 2) * 32, wc = (w & 3) * 32;

    f32x4 acc[2][2] = {};

    // ---- build logits tile (zero + 2 values/row at swizzled ks=0 slot) ----
    *(half8_t*)(Lt + tid * 8) = half8_t{0,0,0,0,0,0,0,0};
    if (tid < 64) {
        int row = tid;
        float2 lv = *(const float2*)&logits[(size_t)(row0 + row) * 2];
        Lt[row * 64 + (row & 7) * 8 + 0] = (_Float16)lv.x;
        Lt[row * 64 + (row & 7) * 8 + 1] = (_Float16)lv.y;
    }

    // stage tile kt: A (f32, 2 gloads/wave, kt<8 only) + B (f16, 2 gloads/wave)
    auto stage = [&](int kt, int bi, bool doA) {
        if (doA) {
            #pragma unroll
            for (int l = 0; l < 2; ++l) {
                int gw = w * 128 + l * 64;
                int g  = gw + lane;
                int row = g >> 4, cg = g & 15;
                int c = (((cg >> 1) ^ (row & 7)) << 1) | (cg & 1);
                gload16f(cols + (size_t)(row0 + row) * 512 + kt * 64 + c * 4,
                         Asf + bi * 4096 + gw * 4);
            }
        }
        #pragma unroll
        for (int l = 0; l < 2; ++l) {
            int gw = w * 128 + l * 64;
            int g  = gw + lane;
            int colr = g >> 3;
            int c    = (g & 7) ^ (colr & 7);
            gload16(WpT + (size_t)(col0 + colr) * KP + kt * 64 + c * 8,
                    Bsm + bi * 8192 + gw * 8);
        }
    };

    auto computeF = [&](int bi) {           // f32-A path (kt < 8)
        const float*    Ab = Asf + bi * 4096;
        const _Float16* Bb = Bsm + bi * 8192;
        #pragma unroll
        for (int kh = 0; kh < 2; ++kh) {
            const int ks = g4 + kh * 4;
            half8_t a[2], b[2];
            #pragma unroll
            for (int mi = 0; mi < 2; ++mi) {
                int row = wr + mi * 16 + r16;
                f32x8 af = *(const f32x8*)(Ab + row * 64 + ((ks ^ (row & 7)) * 8));
                #pragma unroll
                for (int j = 0; j < 8; ++j) a[mi][j] = (_Float16)af[j];
            }
            #pragma unroll
            for (int ni = 0; ni < 2; ++ni) {
                int col = wc + ni * 16 + r16;
                b[ni] = *(const half8_t*)(Bb + col * 64 + ((ks ^ (col & 7)) * 8));
            }
            #pragma unroll
            for (int mi = 0; mi < 2; ++mi)
                #pragma unroll
                for (int ni = 0; ni < 2; ++ni)
                    acc[mi][ni] = __builtin_amdgcn_mfma_f32_16x16x32_f16(
                        a[mi], b[ni], acc[mi][ni], 0, 0, 0);
        }
    };

    auto computeL = [&](int bi) {           // logits path (kt == 8, A from Lt)
        const _Float16* Bb = Bsm + bi * 8192;
        #pragma unroll
        for (int kh = 0; kh < 2; ++kh) {
            const int ks = g4 + kh * 4;
            half8_t a[2], b[2];
            #pragma unroll
            for (int mi = 0; mi < 2; ++mi) {
                int row = wr + mi * 16 + r16;
                a[mi] = *(const half8_t*)(Lt + row * 64 + ((ks ^ (row & 7)) * 8));
            }
            #pragma unroll
            for (int ni = 0; ni < 2; ++ni) {
                int col = wc + ni * 16 + r16;
                b[ni] = *(const half8_t*)(Bb + col * 64 + ((ks ^ (col & 7)) * 8));
            }
            #pragma unroll
            for (int mi = 0; mi < 2; ++mi)
                #pragma unroll
                for (int ni = 0; ni < 2; ++ni)
                    acc[mi][ni] = __builtin_amdgcn_mfma_f32_16x16x32_f16(
                        a[mi], b[ni], acc[mi][ni], 0, 0, 0);
        }
    };

    stage(0, 0, true);
    stage(1, 1, true);
    int buf = 0;
    #pragma unroll 1
    for (int kt = 0; kt < 7; ++kt) {        // steady: tiles 0..6
        asm volatile("s_waitcnt vmcnt(4)" ::: "memory");
        __builtin_amdgcn_s_barrier();
        __builtin_amdgcn_s_setprio(1);
        computeF(buf);
        __builtin_amdgcn_s_setprio(0);
        asm volatile("" ::: "memory");
        __builtin_amdgcn_s_barrier();
        stage(kt + 2, buf, kt + 2 < 8);      // kt=6 stages tile 8 (B only, 2 loads)
        buf ^= 1;
    }
    // tile 7: tile 7's 4 loads + tile 8's 2 loads outstanding -> wait 2
    asm volatile("s_waitcnt vmcnt(2)" ::: "memory");
    __builtin_amdgcn_s_barrier();
    __builtin_amdgcn_s_setprio(1);
    computeF(buf);
    __builtin_amdgcn_s_setprio(0);
    asm volatile("" ::: "memory");
    __builtin_amdgcn_s_barrier();
    buf ^= 1;
    // tile 8 (logits)
    asm volatile("s_waitcnt vmcnt(0)" ::: "memory");
    __builtin_amdgcn_s_barrier();
    computeL(buf);

    // ---- bias + f16 epilogue via LDS repack (reuse Asf region) ----
    __syncthreads();
    _Float16* ep = (_Float16*)Asf;          // [64 r][136]
    #pragma unroll
    for (int mi = 0; mi < 2; ++mi) {
        int rb = wr + mi * 16 + g4 * 4;
        #pragma unroll
        for (int ni = 0; ni < 2; ++ni) {
            int c = wc + ni * 16 + r16;
            float bv = bp[col0 + c];
            #pragma unroll
            for (int q = 0; q < 4; ++q)
                ep[(rb + q) * 136 + c] = (_Float16)(acc[mi][ni][q] + bv);
        }
    }
    __syncthreads();
    #pragma unroll
    for (int it = 0; it < 2; ++it) {
        int g = it * 512 + tid;
        int row = g >> 4, c8 = g & 15;
        *(half8_t*)(Xh + (size_t)(row0 + row) * 512 + col0 + c8 * 8) =
            *(const half8_t*)&ep[row * 136 + c8 * 8];
    }
}

// ====== 128x128 f16 MFMA GEMM, 512 thr / 8 waves (wave tile 64x32) ======
// EPI: 1 = f16 transposed scatter -> YT[b][o][t*256+m] (Y-GEMM)
//      2 = f32 out[r][512], B base per b = row0>>8 (agg-out)
template<int KS, int NKT, int DEPTH, int NB, int NBLK, int EPI>
__global__ __launch_bounds__(512) void gemm512(
    const _Float16* __restrict__ A, const _Float16* __restrict__ Bm,
    void* __restrict__ outv)
{
    __shared__ _Float16 smem[DEPTH * 2 * 8192];
    _Float16* As = smem;
    _Float16* Bs = smem + DEPTH * 8192;
    const int tid = threadIdx.x;
    const int w = tid >> 6, lane = tid & 63;
    const int ell = blockIdx.x;
    const int s = (ell & 7) * (NB / 8) + (ell >> 3);
    const int row0 = (s / NBLK) * 128, col0 = (s % NBLK) * 128;
    const int wr = (w >> 2) * 64, wc = (w & 3) * 32;
    const _Float16* Ag = A + (size_t)row0 * KS;
    const _Float16* Bg = (EPI == 2)
        ? Bm + (size_t)(row0 >> 8) * 512 * KS + (size_t)col0 * KS
        : Bm + (size_t)col0 * KS;

    f32x4 acc[4][2] = {};

    auto stage = [&](int kt, int bi) {
        const _Float16* ga = Ag + kt * 64;
        const _Float16* gb = Bg + kt * 64;
        _Float16* la = As + bi * 8192;
        _Float16* lb = Bs + bi * 8192;
        #pragma unroll
        for (int l = 0; l < 2; ++l) {
            int gw = w * 128 + l * 64;
            int g  = gw + lane;
            int row = g >> 3;
            int c   = (g & 7) ^ (row & 7);
            gload16(ga + (size_t)row * KS + c * 8, la + gw * 8);
        }
        #pragma unroll
        for (int l = 0; l < 2; ++l) {
            int gw = w * 128 + l * 64;
            int g  = gw + lane;
            int row = g >> 3;
            int c   = (g & 7) ^ (row & 7);
            gload16(gb + (size_t)row * KS + c * 8, lb + gw * 8);
        }
    };

    auto compute = [&](int bi) {
        const _Float16* Ab = As + bi * 8192;
        const _Float16* Bb = Bs + bi * 8192;
        const int r16 = lane & 15;
        #pragma unroll
        for (int kh = 0; kh < 2; ++kh) {
            const int ks = (lane >> 4) + kh * 4;
            half8_t a[4], b[2];
            #pragma unroll
            for (int mi = 0; mi < 4; ++mi) {
                int row = wr + mi * 16 + r16;
                a[mi] = *(const half8_t*)(Ab + row * 64 + ((ks ^ (row & 7)) * 8));
            }
            #pragma unroll
            for (int ni = 0; ni < 2; ++ni) {
                int col = wc + ni * 16 + r16;
                b[ni] = *(const half8_t*)(Bb + col * 64 + ((ks ^ (col & 7)) * 8));
            }
            #pragma unroll
            for (int mi = 0; mi < 4; ++mi)
                #pragma unroll
                for (int ni = 0; ni < 2; ++ni)
                    acc[mi][ni] = __builtin_amdgcn_mfma_f32_16x16x32_f16(
                        a[mi], b[ni], acc[mi][ni], 0, 0, 0);
        }
    };

    #pragma unroll
    for (int i = 0; i < DEPTH; ++i) stage(i, i);

    int buf = 0;
    #pragma unroll 1
    for (int kt = 0; kt < NKT - (DEPTH - 1); ++kt) {
        if constexpr (DEPTH == 2) asm volatile("s_waitcnt vmcnt(4)" ::: "memory");
        else                      asm volatile("s_waitcnt vmcnt(8)" ::: "memory");
        __builtin_amdgcn_s_barrier();
        __builtin_amdgcn_s_setprio(1);
        compute(buf);
        __builtin_amdgcn_s_setprio(0);
        asm volatile("" ::: "memory");
        __builtin_amdgcn_s_barrier();
        if (kt + DEPTH < NKT) stage(kt + DEPTH, buf);
        ++buf; if (buf == DEPTH) buf = 0;
    }
    if constexpr (DEPTH == 3) {
        asm volatile("s_waitcnt vmcnt(4)" ::: "memory");
        __builtin_amdgcn_s_barrier();
        __builtin_amdgcn_s_setprio(1);
        compute(buf);
        __builtin_amdgcn_s_setprio(0);
        asm volatile("" ::: "memory");
        __builtin_amdgcn_s_barrier();
        ++buf; if (buf == DEPTH) buf = 0;
    }
    asm volatile("s_waitcnt vmcnt(0)" ::: "memory");
    __builtin_amdgcn_s_barrier();
    compute(buf);

    // C/D layout: col = lane&15, row = (lane>>4)*4 + q
    if constexpr (EPI == 2) {
        float* out = (float*)outv;
        #pragma unroll
        for (int mi = 0; mi < 4; ++mi) {
            int r = row0 + wr + mi * 16 + (lane >> 4) * 4;
            #pragma unroll
            for (int ni = 0; ni < 2; ++ni) {
                int cidx = col0 + wc + ni * 16 + (lane & 15);
                #pragma unroll
                for (int q = 0; q < 4; ++q)
                    out[(size_t)(r + q) * HID + cidx] = acc[mi][ni][q];
            }
        }
    } else {
        __syncthreads();
        _Float16* ep = smem;                   // [128 c][136]
        #pragma unroll
        for (int mi = 0; mi < 4; ++mi) {
            int rb = wr + mi * 16 + (lane >> 4) * 4;
            #pragma unroll
            for (int ni = 0; ni < 2; ++ni) {
                int c = wc + ni * 16 + (lane & 15);
                half4_t h4;
                #pragma unroll
                for (int q = 0; q < 4; ++q) h4[q] = (_Float16)acc[mi][ni][q];
                *(half4_t*)&ep[c * 136 + rb] = h4;
            }
        }
        __syncthreads();
        const int b = row0 >> 8, m0 = row0 & 255, t = col0 >> 9, o0 = col0 & 511;
        _Float16* yb = (_Float16*)outv + ((size_t)b * 512 + o0) * 768 + (size_t)t * 256 + m0;
        #pragma unroll
        for (int it = 0; it < 4; ++it) {
            int g = it * 512 + tid;
            int c = g >> 4, m8 = g & 15;
            *(half8_t*)(yb + (size_t)c * 768 + m8 * 8) =
                *(const half8_t*)&ep[c * 136 + m8 * 8];
        }
    }
}

// ------- LayerNorm + exact GELU, IN-PLACE on f16 [row][512] (block = row) -------
__global__ __launch_bounds__(256) void ln_gelu_ip(_Float16* __restrict__ h,
    const float* __restrict__ g, const float* __restrict__ bb)
{
    int row = blockIdx.x;
    int tid = threadIdx.x;
    float v0 = (float)h[(size_t)row*512 + tid];
    float v1 = (float)h[(size_t)row*512 + 256 + tid];
    __shared__ float red[4];
    int wid = tid >> 6, lane = tid & 63;

    float s = v0 + v1;
    #pragma unroll
    for (int off = 32; off; off >>= 1) s += __shfl_down(s, off);
    if (lane == 0) red[wid] = s;
    __syncthreads();
    float mu = (red[0]+red[1]+red[2]+red[3]) * (1.f/512.f);
    __syncthreads();

    float d0 = v0 - mu, d1 = v1 - mu;
    float q = d0*d0 + d1*d1;
    #pragma unroll
    for (int off = 32; off; off >>= 1) q += __shfl_down(q, off);
    if (lane == 0) red[wid] = q;
    __syncthreads();
    float var = (red[0]+red[1]+red[2]+red[3]) * (1.f/512.f);
    float rs = rsqrtf(var + 1e-5f);

    float y0 = d0*rs*g[tid] + bb[tid];
    float y1 = d1*rs*g[tid+256] + bb[tid+256];
    y0 = 0.5f*y0*(1.f + erff(y0*0.70710678118654752f));
    y1 = 0.5f*y1*(1.f + erff(y1*0.70710678118654752f));
    h[(size_t)row*512 + tid]       = (_Float16)y0;
    h[(size_t)row*512 + 256 + tid] = (_Float16)y1;
}

extern "C" void kernel_launch(void* const* d_in, const int* in_sizes, int n_in,
                              void* d_out, int out_size, void* d_ws, size_t ws_size,
                              hipStream_t stream)
{
    const float* cols   = (const float*)d_in[0];
    const float* logits = (const float*)d_in[1];
    const int*   adj    = (const int*)  d_in[2];
    const float* Wp     = (const float*)d_in[3];
    const float* bp     = (const float*)d_in[4];
    const float* lg     = (const float*)d_in[5];
    const float* lb     = (const float*)d_in[6];
    const float* W      = (const float*)d_in[7];
    const float* V      = (const float*)d_in[8];
    float* out  = (float*)d_out;

    char* p = (char*)d_ws;
    _Float16* Xh   = (_Float16*)p;  p += (size_t)ROWS*HID*2;          // 8.4 MB
    _Float16* WpT  = (_Float16*)p;  p += (size_t)HID*KP*2;            // 0.6 MB
    _Float16* WcT  = (_Float16*)p;  p += (size_t)1536*HID*2;          // 1.6 MB
    _Float16* C16b = (_Float16*)p;  p += (size_t)ROWS*768*2;          // 12.6 MB
    _Float16* YTb  = (_Float16*)p;  p += (size_t)BSZ*HID*768*2;       // 25.2 MB

    prep<<<392, 256, 0, stream>>>(Wp, W, adj, V, WpT, WcT, C16b);
    projx<<<512, 512, 0, stream>>>(cols, logits, WpT, bp, Xh);
    ln_gelu_ip<<<ROWS, 256, 0, stream>>>(Xh, lg, lb);
    gemm512<512, 8, 2, 768, 12, 1><<<768, 512, 0, stream>>>(Xh, WcT, YTb);
    gemm512<768, 12, 3, 256, 4, 2><<<256, 512, 0, stream>>>(C16b, YTb, out);
}

// Round 15
// 62.625 us; speedup vs baseline: 1.2348x; 1.0364x over previous
//
#include <hip/hip_runtime.h>
#include <math.h>

#define HID 512
#define NSEQ 256
#define BSZ 32
#define ROWS (BSZ*NSEQ)   // 8192
#define KP 576            // padded proj K (514 -> 576 = 9*64)

typedef _Float16 half8_t __attribute__((ext_vector_type(8)));
typedef _Float16 half4_t __attribute__((ext_vector_type(4)));
typedef float f32x4 __attribute__((ext_vector_type(4)));
typedef float f32x8 __attribute__((ext_vector_type(8)));

__device__ __forceinline__ void gload16(const _Float16* g, _Float16* l) {
    __builtin_amdgcn_global_load_lds(
        (const __attribute__((address_space(1))) unsigned int*)g,
        (__attribute__((address_space(3))) unsigned int*)l, 16, 0, 0);
}
__device__ __forceinline__ void gload16f(const float* g, float* l) {
    __builtin_amdgcn_global_load_lds(
        (const __attribute__((address_space(1))) unsigned int*)g,
        (__attribute__((address_space(3))) unsigned int*)l, 16, 0, 0);
}

// =============== fused prep: WcT | WpT | C16b (round-13 verified) =====
__global__ __launch_bounds__(256) void prep(
    const float* __restrict__ Wp, const float* __restrict__ W,
    const int* __restrict__ adj, const float* __restrict__ V,
    _Float16* __restrict__ WpT, _Float16* __restrict__ WcT,
    _Float16* __restrict__ C16b)
{
    __shared__ _Float16 ts[64][68];
    __shared__ _Float16 lutH[48];       // [r][t], r=0 zeroed
    __shared__ _Float16 V0h[3];
    const int blk = blockIdx.x, tid = threadIdx.x;

    if (blk < 192) {                        // ---- WcT (24 c-tiles x 8 h-tiles)
        int c0 = (blk % 24) * 64, h0 = (blk / 24) * 64;
        int r = tid >> 2, q = tid & 3;
        #pragma unroll
        for (int i = 0; i < 4; ++i) {
            float4 v = *(const float4*)&W[(size_t)(h0+r)*1536 + c0 + q*16 + i*4];
            ts[r][q*16+i*4+0] = (_Float16)v.x;
            ts[r][q*16+i*4+1] = (_Float16)v.y;
            ts[r][q*16+i*4+2] = (_Float16)v.z;
            ts[r][q*16+i*4+3] = (_Float16)v.w;
        }
        __syncthreads();
        _Float16* op = WcT + (size_t)(c0 + r)*512 + h0 + q*16;
        #pragma unroll
        for (int i = 0; i < 4; ++i) {
            half4_t o;
            #pragma unroll
            for (int j = 0; j < 4; ++j) o[j] = ts[q*16+i*4+j][r];
            *(half4_t*)(op + i*4) = o;
        }
    } else if (blk < 264) {                 // ---- WpT (9 k-tiles x 8 o-tiles)
        int sub = blk - 192;
        int k0 = (sub % 9) * 64, o0 = (sub / 9) * 64;
        int r = tid >> 2, q = tid & 3;
        int k = k0 + r;
        #pragma unroll
        for (int i = 0; i < 4; ++i) {
            float4 v = make_float4(0.f,0.f,0.f,0.f);
            if (k < 514) v = *(const float4*)&Wp[(size_t)k*HID + o0 + q*16 + i*4];
            ts[r][q*16+i*4+0] = (_Float16)v.x;
            ts[r][q*16+i*4+1] = (_Float16)v.y;
            ts[r][q*16+i*4+2] = (_Float16)v.z;
            ts[r][q*16+i*4+3] = (_Float16)v.w;
        }
        __syncthreads();
        _Float16* op = WpT + (size_t)(o0 + r)*KP + k0 + q*16;
        #pragma unroll
        for (int i = 0; i < 4; ++i) {
            half4_t o;
            #pragma unroll
            for (int j = 0; j < 4; ++j) o[j] = ts[q*16+i*4+j][r];
            *(half4_t*)(op + i*4) = o;
        }
    } else {                                // ---- C16b (128 blocks: 32 b x 4 n-tiles)
        if (tid < 48) { int r = tid/3; lutH[tid] = (_Float16)((r >= 1) ? V[tid] : 0.f); }
        if (tid < 3) V0h[tid] = (_Float16)V[tid];
        __syncthreads();
        int sub = blk - 264;
        int b = sub >> 2, nt = sub & 3;
        int w = tid >> 6, lane = tid & 63;
        #pragma unroll
        for (int i = 0; i < 16; ++i) {
            int n = nt*64 + w*16 + i;
            int4 a4 = *(const int4*)(adj + ((size_t)(b*NSEQ + n))*NSEQ + lane*4);
            int av[4] = { a4.x, a4.y, a4.z, a4.w };
            size_t ob = ((size_t)(b*NSEQ + n))*768 + lane*4;
            #pragma unroll
            for (int t = 0; t < 3; ++t) {
                half4_t o;
                #pragma unroll
                for (int j = 0; j < 4; ++j) o[j] = lutH[av[j]*3 + t];
                if ((n >> 2) == lane) o[n & 3] = (_Float16)(o[n & 3] + V0h[t]);
                *(half4_t*)(C16b + ob + (size_t)t*256) = o;
            }
        }
    }
}

// ========= projx: Xh[r][o] = f16( concat(cols,logits)[r] @ WpT^T + bp ) =========
// (round-13 verified) BM=64, BN=128. Grid 512. 8 waves, wave tile 32x32.
__global__ __launch_bounds__(512) void projx(
    const float* __restrict__ cols, const float* __restrict__ logits,
    const _Float16* __restrict__ WpT, const float* __restrict__ bp,
    _Float16* __restrict__ Xh)
{
    __shared__ float    Asf[2*4096];    // 2 x [64 row][64 k] f32 = 32KB
    __shared__ _Float16 Bsm[2*8192];    // 2 x [128 col][64 k] f16 = 32KB
    __shared__ _Float16 Lt[4096];       // logits A-tile [64][64] f16 = 8KB
    const int tid = threadIdx.x;
    const int w = tid >> 6, lane = tid & 63;
    const int r16 = lane & 15, g4 = lane >> 4;
    const int ell = blockIdx.x;
    const int s = (ell & 7) * 64 + (ell >> 3);       // XCD-chunked swizzle
    const int row0 = (s >> 2) * 64, col0 = (s & 3) * 128;
    const int wr = (w >> 2) * 32, wc = (w & 3) * 32;

    f32x4 acc[2][2] = {};

    // ---- build logits tile (zero + 2 values/row at swizzled ks=0 slot) ----
    *(half8_t*)(Lt + tid * 8) = half8_t{0,0,0,0,0,0,0,0};
    if (tid < 64) {
        int row = tid;
        float2 lv = *(const float2*)&logits[(size_t)(row0 + row) * 2];
        Lt[row * 64 + (row & 7) * 8 + 0] = (_Float16)lv.x;
        Lt[row * 64 + (row & 7) * 8 + 1] = (_Float16)lv.y;
    }

    auto stage = [&](int kt, int bi, bool doA) {
        if (doA) {
            #pragma unroll
            for (int l = 0; l < 2; ++l) {
                int gw = w * 128 + l * 64;
                int g  = gw + lane;
                int row = g >> 4, cg = g & 15;
                int c = (((cg >> 1) ^ (row & 7)) << 1) | (cg & 1);
                gload16f(cols + (size_t)(row0 + row) * 512 + kt * 64 + c * 4,
                         Asf + bi * 4096 + gw * 4);
            }
        }
        #pragma unroll
        for (int l = 0; l < 2; ++l) {
            int gw = w * 128 + l * 64;
            int g  = gw + lane;
            int colr = g >> 3;
            int c    = (g & 7) ^ (colr & 7);
            gload16(WpT + (size_t)(col0 + colr) * KP + kt * 64 + c * 8,
                    Bsm + bi * 8192 + gw * 8);
        }
    };

    auto computeF = [&](int bi) {           // f32-A path (kt < 8)
        const float*    Ab = Asf + bi * 4096;
        const _Float16* Bb = Bsm + bi * 8192;
        #pragma unroll
        for (int kh = 0; kh < 2; ++kh) {
            const int ks = g4 + kh * 4;
            half8_t a[2], b[2];
            #pragma unroll
            for (int mi = 0; mi < 2; ++mi) {
                int row = wr + mi * 16 + r16;
                f32x8 af = *(const f32x8*)(Ab + row * 64 + ((ks ^ (row & 7)) * 8));
                #pragma unroll
                for (int j = 0; j < 8; ++j) a[mi][j] = (_Float16)af[j];
            }
            #pragma unroll
            for (int ni = 0; ni < 2; ++ni) {
                int col = wc + ni * 16 + r16;
                b[ni] = *(const half8_t*)(Bb + col * 64 + ((ks ^ (col & 7)) * 8));
            }
            #pragma unroll
            for (int mi = 0; mi < 2; ++mi)
                #pragma unroll
                for (int ni = 0; ni < 2; ++ni)
                    acc[mi][ni] = __builtin_amdgcn_mfma_f32_16x16x32_f16(
                        a[mi], b[ni], acc[mi][ni], 0, 0, 0);
        }
    };

    auto computeL = [&](int bi) {           // logits path (kt == 8, A from Lt)
        const _Float16* Bb = Bsm + bi * 8192;
        #pragma unroll
        for (int kh = 0; kh < 2; ++kh) {
            const int ks = g4 + kh * 4;
            half8_t a[2], b[2];
            #pragma unroll
            for (int mi = 0; mi < 2; ++mi) {
                int row = wr + mi * 16 + r16;
                a[mi] = *(const half8_t*)(Lt + row * 64 + ((ks ^ (row & 7)) * 8));
            }
            #pragma unroll
            for (int ni = 0; ni < 2; ++ni) {
                int col = wc + ni * 16 + r16;
                b[ni] = *(const half8_t*)(Bb + col * 64 + ((ks ^ (col & 7)) * 8));
            }
            #pragma unroll
            for (int mi = 0; mi < 2; ++mi)
                #pragma unroll
                for (int ni = 0; ni < 2; ++ni)
                    acc[mi][ni] = __builtin_amdgcn_mfma_f32_16x16x32_f16(
                        a[mi], b[ni], acc[mi][ni], 0, 0, 0);
        }
    };

    stage(0, 0, true);
    stage(1, 1, true);
    int buf = 0;
    #pragma unroll 1
    for (int kt = 0; kt < 7; ++kt) {        // steady: tiles 0..6
        asm volatile("s_waitcnt vmcnt(4)" ::: "memory");
        __builtin_amdgcn_s_barrier();
        __builtin_amdgcn_s_setprio(1);
        computeF(buf);
        __builtin_amdgcn_s_setprio(0);
        asm volatile("" ::: "memory");
        __builtin_amdgcn_s_barrier();
        stage(kt + 2, buf, kt + 2 < 8);      // kt=6 stages tile 8 (B only, 2 loads)
        buf ^= 1;
    }
    // tile 7: tile 7's 4 loads + tile 8's 2 loads outstanding -> wait 2
    asm volatile("s_waitcnt vmcnt(2)" ::: "memory");
    __builtin_amdgcn_s_barrier();
    __builtin_amdgcn_s_setprio(1);
    computeF(buf);
    __builtin_amdgcn_s_setprio(0);
    asm volatile("" ::: "memory");
    __builtin_amdgcn_s_barrier();
    buf ^= 1;
    // tile 8 (logits)
    asm volatile("s_waitcnt vmcnt(0)" ::: "memory");
    __builtin_amdgcn_s_barrier();
    computeL(buf);

    // ---- bias + f16 epilogue via LDS repack (reuse Asf region) ----
    __syncthreads();
    _Float16* ep = (_Float16*)Asf;          // [64 r][136]
    #pragma unroll
    for (int mi = 0; mi < 2; ++mi) {
        int rb = wr + mi * 16 + g4 * 4;
        #pragma unroll
        for (int ni = 0; ni < 2; ++ni) {
            int c = wc + ni * 16 + r16;
            float bv = bp[col0 + c];
            #pragma unroll
            for (int q = 0; q < 4; ++q)
                ep[(rb + q) * 136 + c] = (_Float16)(acc[mi][ni][q] + bv);
        }
    }
    __syncthreads();
    #pragma unroll
    for (int it = 0; it < 2; ++it) {
        int g = it * 512 + tid;
        int row = g >> 4, c8 = g & 15;
        *(half8_t*)(Xh + (size_t)(row0 + row) * 512 + col0 + c8 * 8) =
            *(const half8_t*)&ep[row * 136 + c8 * 8];
    }
}

// ====== 128x128 f16 MFMA GEMM, 512 thr / 8 waves (wave tile 64x32) ======
// EPI: 1 = f16 transposed scatter -> YT[b][o][t*256+m] (Y-GEMM)
//      2 = f32 out[r][512], B base per b = row0>>8 (agg-out)
template<int KS, int NKT, int DEPTH, int NB, int NBLK, int EPI>
__global__ __launch_bounds__(512) void gemm512(
    const _Float16* __restrict__ A, const _Float16* __restrict__ Bm,
    void* __restrict__ outv)
{
    __shared__ _Float16 smem[DEPTH * 2 * 8192];
    _Float16* As = smem;
    _Float16* Bs = smem + DEPTH * 8192;
    const int tid = threadIdx.x;
    const int w = tid >> 6, lane = tid & 63;
    const int ell = blockIdx.x;
    const int s = (ell & 7) * (NB / 8) + (ell >> 3);
    const int row0 = (s / NBLK) * 128, col0 = (s % NBLK) * 128;
    const int wr = (w >> 2) * 64, wc = (w & 3) * 32;
    const _Float16* Ag = A + (size_t)row0 * KS;
    const _Float16* Bg = (EPI == 2)
        ? Bm + (size_t)(row0 >> 8) * 512 * KS + (size_t)col0 * KS
        : Bm + (size_t)col0 * KS;

    f32x4 acc[4][2] = {};

    auto stage = [&](int kt, int bi) {
        const _Float16* ga = Ag + kt * 64;
        const _Float16* gb = Bg + kt * 64;
        _Float16* la = As + bi * 8192;
        _Float16* lb = Bs + bi * 8192;
        #pragma unroll
        for (int l = 0; l < 2; ++l) {
            int gw = w * 128 + l * 64;
            int g  = gw + lane;
            int row = g >> 3;
            int c   = (g & 7) ^ (row & 7);
            gload16(ga + (size_t)row * KS + c * 8, la + gw * 8);
        }
        #pragma unroll
        for (int l = 0; l < 2; ++l) {
            int gw = w * 128 + l * 64;
            int g  = gw + lane;
            int row = g >> 3;
            int c   = (g & 7) ^ (row & 7);
            gload16(gb + (size_t)row * KS + c * 8, lb + gw * 8);
        }
    };

    auto compute = [&](int bi) {
        const _Float16* Ab = As + bi * 8192;
        const _Float16* Bb = Bs + bi * 8192;
        const int r16 = lane & 15;
        #pragma unroll
        for (int kh = 0; kh < 2; ++kh) {
            const int ks = (lane >> 4) + kh * 4;
            half8_t a[4], b[2];
            #pragma unroll
            for (int mi = 0; mi < 4; ++mi) {
                int row = wr + mi * 16 + r16;
                a[mi] = *(const half8_t*)(Ab + row * 64 + ((ks ^ (row & 7)) * 8));
            }
            #pragma unroll
            for (int ni = 0; ni < 2; ++ni) {
                int col = wc + ni * 16 + r16;
                b[ni] = *(const half8_t*)(Bb + col * 64 + ((ks ^ (col & 7)) * 8));
            }
            #pragma unroll
            for (int mi = 0; mi < 4; ++mi)
                #pragma unroll
                for (int ni = 0; ni < 2; ++ni)
                    acc[mi][ni] = __builtin_amdgcn_mfma_f32_16x16x32_f16(
                        a[mi], b[ni], acc[mi][ni], 0, 0, 0);
        }
    };

    #pragma unroll
    for (int i = 0; i < DEPTH; ++i) stage(i, i);

    int buf = 0;
    #pragma unroll 1
    for (int kt = 0; kt < NKT - (DEPTH - 1); ++kt) {
        if constexpr (DEPTH == 2) asm volatile("s_waitcnt vmcnt(4)" ::: "memory");
        else                      asm volatile("s_waitcnt vmcnt(8)" ::: "memory");
        __builtin_amdgcn_s_barrier();
        __builtin_amdgcn_s_setprio(1);
        compute(buf);
        __builtin_amdgcn_s_setprio(0);
        asm volatile("" ::: "memory");
        __builtin_amdgcn_s_barrier();
        if (kt + DEPTH < NKT) stage(kt + DEPTH, buf);
        ++buf; if (buf == DEPTH) buf = 0;
    }
    if constexpr (DEPTH == 3) {
        asm volatile("s_waitcnt vmcnt(4)" ::: "memory");
        __builtin_amdgcn_s_barrier();
        __builtin_amdgcn_s_setprio(1);
        compute(buf);
        __builtin_amdgcn_s_setprio(0);
        asm volatile("" ::: "memory");
        __builtin_amdgcn_s_barrier();
        ++buf; if (buf == DEPTH) buf = 0;
    }
    asm volatile("s_waitcnt vmcnt(0)" ::: "memory");
    __builtin_amdgcn_s_barrier();
    compute(buf);

    // C/D layout: col = lane&15, row = (lane>>4)*4 + q
    if constexpr (EPI == 2) {
        float* out = (float*)outv;
        #pragma unroll
        for (int mi = 0; mi < 4; ++mi) {
            int r = row0 + wr + mi * 16 + (lane >> 4) * 4;
            #pragma unroll
            for (int ni = 0; ni < 2; ++ni) {
                int cidx = col0 + wc + ni * 16 + (lane & 15);
                #pragma unroll
                for (int q = 0; q < 4; ++q)
                    out[(size_t)(r + q) * HID + cidx] = acc[mi][ni][q];
            }
        }
    } else {
        __syncthreads();
        _Float16* ep = smem;                   // [128 c][136]
        #pragma unroll
        for (int mi = 0; mi < 4; ++mi) {
            int rb = wr + mi * 16 + (lane >> 4) * 4;
            #pragma unroll
            for (int ni = 0; ni < 2; ++ni) {
                int c = wc + ni * 16 + (lane & 15);
                half4_t h4;
                #pragma unroll
                for (int q = 0; q < 4; ++q) h4[q] = (_Float16)acc[mi][ni][q];
                *(half4_t*)&ep[c * 136 + rb] = h4;
            }
        }
        __syncthreads();
        const int b = row0 >> 8, m0 = row0 & 255, t = col0 >> 9, o0 = col0 & 511;
        _Float16* yb = (_Float16*)outv + ((size_t)b * 512 + o0) * 768 + (size_t)t * 256 + m0;
        #pragma unroll
        for (int it = 0; it < 4; ++it) {
            int g = it * 512 + tid;
            int c = g >> 4, m8 = g & 15;
            *(half8_t*)(yb + (size_t)c * 768 + m8 * 8) =
                *(const half8_t*)&ep[c * 136 + m8 * 8];
        }
    }
}

// ------- LayerNorm + exact GELU, IN-PLACE, wave-per-row (4 rows/block) -------
// Each wave: 64 lanes x 8 f16 = one 512-elem row. No LDS, shfl_xor reduction.
__global__ __launch_bounds__(256) void ln_gelu_ip(_Float16* __restrict__ h,
    const float* __restrict__ g, const float* __restrict__ bb)
{
    const int wv = threadIdx.x >> 6, lane = threadIdx.x & 63;
    const int row = blockIdx.x * 4 + wv;
    _Float16* hp = h + (size_t)row * 512 + lane * 8;
    half8_t v = *(const half8_t*)hp;
    float vf[8];
    float s = 0.f, s2 = 0.f;
    #pragma unroll
    for (int j = 0; j < 8; ++j) {
        vf[j] = (float)v[j];
        s += vf[j]; s2 += vf[j] * vf[j];
    }
    #pragma unroll
    for (int m = 1; m < 64; m <<= 1) {
        s  += __shfl_xor(s,  m);
        s2 += __shfl_xor(s2, m);
    }
    float mu = s * (1.f/512.f);
    float var = s2 * (1.f/512.f) - mu * mu;
    float rs = rsqrtf(var + 1e-5f);
    float4 g0 = *(const float4*)&g[lane*8],  g1 = *(const float4*)&g[lane*8+4];
    float4 b0 = *(const float4*)&bb[lane*8], b1 = *(const float4*)&bb[lane*8+4];
    float gv[8] = { g0.x,g0.y,g0.z,g0.w, g1.x,g1.y,g1.z,g1.w };
    float bv[8] = { b0.x,b0.y,b0.z,b0.w, b1.x,b1.y,b1.z,b1.w };
    #pragma unroll
    for (int j = 0; j < 8; ++j) {
        float y = (vf[j] - mu) * rs * gv[j] + bv[j];
        y = 0.5f * y * (1.f + erff(y * 0.70710678118654752f));
        v[j] = (_Float16)y;
    }
    *(half8_t*)hp = v;
}

extern "C" void kernel_launch(void* const* d_in, const int* in_sizes, int n_in,
                              void* d_out, int out_size, void* d_ws, size_t ws_size,
                              hipStream_t stream)
{
    const float* cols   = (const float*)d_in[0];
    const float* logits = (const float*)d_in[1];
    const int*   adj    = (const int*)  d_in[2];
    const float* Wp     = (const float*)d_in[3];
    const float* bp     = (const float*)d_in[4];
    const float* lg     = (const float*)d_in[5];
    const float* lb     = (const float*)d_in[6];
    const float* W      = (const float*)d_in[7];
    const float* V      = (const float*)d_in[8];
    float* out  = (float*)d_out;

    char* p = (char*)d_ws;
    _Float16* Xh   = (_Float16*)p;  p += (size_t)ROWS*HID*2;          // 8.4 MB
    _Float16* WpT  = (_Float16*)p;  p += (size_t)HID*KP*2;            // 0.6 MB
    _Float16* WcT  = (_Float16*)p;  p += (size_t)1536*HID*2;          // 1.6 MB
    _Float16* C16b = (_Float16*)p;  p += (size_t)ROWS*768*2;          // 12.6 MB
    _Float16* YTb  = (_Float16*)p;  p += (size_t)BSZ*HID*768*2;       // 25.2 MB

    prep<<<392, 256, 0, stream>>>(Wp, W, adj, V, WpT, WcT, C16b);
    projx<<<512, 512, 0, stream>>>(cols, logits, WpT, bp, Xh);
    ln_gelu_ip<<<2048, 256, 0, stream>>>(Xh, lg, lb);
    gemm512<512, 8, 2, 768, 12, 1><<<768, 512, 0, stream>>>(Xh, WcT, YTb);
    gemm512<768, 12, 3, 256, 4, 2><<<256, 512, 0, stream>>>(C16b, YTb, out);
}